// Round 3
// baseline (110.084 us; speedup 1.0000x reference)
//
#include <hip/hip_runtime.h>
#include <math.h>

#define DM 256   // d_model
#define NP 256   // n == m == 256 points
#define NH 4     // heads
#define DH 64    // dim per head
#define PI_F 3.14159265358979323846f

typedef unsigned long long u64;
typedef __attribute__((ext_vector_type(2))) unsigned long long u64x2;

// ---------------------------------------------------------------------------
// Kernel A: Q/K/V pointwise conv (GEMM) + bias -> T[b][h][pt][d].
// 64x64 tile, 4x4 micro-tile, K-chunk 32, reg-staged double-buffered LDS.
// LDS layout transposed to [kk][c] / [kk][p] for conflict-free b128 reads.
// ---------------------------------------------------------------------------
__global__ __launch_bounds__(256) void qkv_proj_kernel(
    const float* __restrict__ x, const float* __restrict__ src,
    const float* __restrict__ Wq, const float* __restrict__ bq,
    const float* __restrict__ Wk, const float* __restrict__ bk,
    const float* __restrict__ Wv, const float* __restrict__ bv,
    float* __restrict__ Qt, float* __restrict__ Kt, float* __restrict__ Vt)
{
  const int tile = blockIdx.x;      // 16 tiles: 4x4 grid of 64x64
  const int mat  = blockIdx.y;      // 0=q, 1=k, 2=v
  const int b    = blockIdx.z;
  const int tc = (tile >> 2) * 64;  // channel tile origin
  const int tp = (tile & 3) * 64;   // point tile origin
  const float* W    = (mat == 0) ? Wq : (mat == 1) ? Wk : Wv;
  const float* bias = (mat == 0) ? bq : (mat == 1) ? bk : bv;
  const float* X    = ((mat == 0) ? x : src) + (size_t)b * DM * NP;
  float* T          = ((mat == 0) ? Qt : (mat == 1) ? Kt : Vt) + (size_t)b * NH * NP * DH;

  __shared__ float Ws[2][32][64];
  __shared__ float Xs[2][32][64];
  const int tid = threadIdx.x;
  const int ty = tid >> 4, tx = tid & 15;
  // staging assignment
  const int c0 = tid >> 3;          // 0..31 (W row), +32 second
  const int k4 = tid & 7;           // 0..7  (k/4 group)
  const int pX = tid & 15;          // 0..15 (p/4 group)
  const int kX = tid >> 4;          // 0..15 (k row), +16 second

  float4 wA, wB, xA, xB;
  #define LOADQKV(K0)                                                          \
    wA = *(const float4*)&W[(size_t)(tc + c0)      * DM + (K0) + k4 * 4];      \
    wB = *(const float4*)&W[(size_t)(tc + c0 + 32) * DM + (K0) + k4 * 4];      \
    xA = *(const float4*)&X[(size_t)((K0) + kX)      * NP + tp + pX * 4];      \
    xB = *(const float4*)&X[(size_t)((K0) + kX + 16) * NP + tp + pX * 4];

  #define STOREQKV(BUF)                                                        \
    Ws[BUF][k4*4+0][c0] = wA.x; Ws[BUF][k4*4+1][c0] = wA.y;                    \
    Ws[BUF][k4*4+2][c0] = wA.z; Ws[BUF][k4*4+3][c0] = wA.w;                    \
    Ws[BUF][k4*4+0][c0+32] = wB.x; Ws[BUF][k4*4+1][c0+32] = wB.y;              \
    Ws[BUF][k4*4+2][c0+32] = wB.z; Ws[BUF][k4*4+3][c0+32] = wB.w;              \
    *(float4*)&Xs[BUF][kX][pX*4]      = xA;                                    \
    *(float4*)&Xs[BUF][kX+16][pX*4]   = xB;

  LOADQKV(0);
  STOREQKV(0);
  __syncthreads();

  float acc[4][4];
  #pragma unroll
  for (int i = 0; i < 4; ++i)
    #pragma unroll
    for (int j = 0; j < 4; ++j) acc[i][j] = 0.f;

  for (int ch = 0; ch < 8; ++ch) {
    const int cur = ch & 1;
    if (ch < 7) { LOADQKV((ch + 1) * 32); }
    #pragma unroll
    for (int kk = 0; kk < 32; ++kk) {
      float4 a = *(const float4*)&Ws[cur][kk][ty * 4];
      float4 xv = *(const float4*)&Xs[cur][kk][tx * 4];
      float av[4] = {a.x, a.y, a.z, a.w};
      float xvv[4] = {xv.x, xv.y, xv.z, xv.w};
      #pragma unroll
      for (int i = 0; i < 4; ++i)
        #pragma unroll
        for (int j = 0; j < 4; ++j) acc[i][j] += av[i] * xvv[j];
    }
    if (ch < 7) {
      STOREQKV(cur ^ 1);
      __syncthreads();
    }
  }

  #pragma unroll
  for (int i = 0; i < 4; ++i) {
    const int c = tc + ty * 4 + i;
    const float bb = bias[c];
    #pragma unroll
    for (int j = 0; j < 4; ++j) {
      const int p = tp + tx * 4 + j;
      T[((size_t)(c & 3) * NP + p) * DH + (c >> 2)] = acc[i][j] + bb;
    }
  }
  #undef LOADQKV
  #undef STOREQKV
}

// ---------------------------------------------------------------------------
// Kernel B (fused): scores -> rank-select top-k -> softmax -> rotary gather.
// 2 rows per block, 2 waves per row (each wave owns 128 candidate m's).
// ---------------------------------------------------------------------------
__global__ __launch_bounds__(256, 8) void attn_fused_kernel(
    const float* __restrict__ Qt, const float* __restrict__ Kt,
    const float* __restrict__ Vt,
    const float* __restrict__ x_pos, const float* __restrict__ src_pos,
    const float* __restrict__ lrf,
    const int* __restrict__ kptr,
    float* __restrict__ O)
{
  const int tid  = threadIdx.x;
  const int wid  = tid >> 6;
  const int lane = tid & 63;
  const int rl   = wid >> 1;     // row within block
  const int sub  = wid & 1;      // half of candidate axis
  const int row  = blockIdx.x * 2 + rl;   // (b*NH + h)*NP + n
  const int n    = row & (NP - 1);
  const int bh   = row >> 8;
  const int b    = bh >> 2;
  const int h    = bh & 3;

  int kk = *kptr;
  if (kk > 64) kk = 64;
  if (kk < 1) kk = 1;

  __shared__ float qs[2][DH];
  __shared__ alignas(16) u64 keys[2][NP];
  __shared__ float sval[2][64];
  __shared__ int   sidx[2][64];
  __shared__ float4 ang[2][64];
  __shared__ float part[2][64];

  if (sub == 0) qs[rl][lane] = Qt[(size_t)row * DH + lane];
  __syncthreads();

  // ---- scores for m = sub*128 + {0,64} + lane ------------------------------
  const float* kbase = Kt + (size_t)bh * NP * DH;
  const int m0 = sub * 128 + lane;
  const float4* q4  = (const float4*)qs[rl];
  const float4* kp0 = (const float4*)(kbase + (size_t)m0 * DH);
  const float4* kp1 = (const float4*)(kbase + (size_t)(m0 + 64) * DH);
  float s0 = 0.f, s1 = 0.f;
  #pragma unroll
  for (int dd = 0; dd < 16; ++dd) {
    float4 qv = q4[dd];
    float4 a0 = kp0[dd], a1 = kp1[dd];
    s0 += a0.x*qv.x + a0.y*qv.y + a0.z*qv.z + a0.w*qv.w;
    s1 += a1.x*qv.x + a1.y*qv.y + a1.z*qv.z + a1.w*qv.w;
  }
  s0 *= 0.125f; s1 *= 0.125f;

  // ---- sortable keys (value<<32 | (255-m): distinct, ties -> smaller m) ----
  unsigned int b0 = __float_as_uint(s0);
  unsigned int b1 = __float_as_uint(s1);
  b0 = (b0 & 0x80000000u) ? ~b0 : (b0 | 0x80000000u);
  b1 = (b1 & 0x80000000u) ? ~b1 : (b1 | 0x80000000u);
  const u64 key0 = ((u64)b0 << 32) | (unsigned int)(255 - m0);
  const u64 key1 = ((u64)b1 << 32) | (unsigned int)(255 - (m0 + 64));
  keys[rl][m0]      = key0;
  keys[rl][m0 + 64] = key1;
  __syncthreads();

  // ---- rank by counting (broadcast b128 LDS reads, pure VALU) --------------
  int r0 = 0, r1 = 0;
  const u64* kw = keys[rl];
  #pragma unroll 8
  for (int j = 0; j < NP; j += 2) {
    u64x2 kp = *(const u64x2*)&kw[j];
    r0 += (kp.x > key0); r0 += (kp.y > key0);
    r1 += (kp.x > key1); r1 += (kp.y > key1);
  }
  if (r0 < kk) { sval[rl][r0] = s0; sidx[rl][r0] = m0; }
  if (r1 < kk) { sval[rl][r1] = s1; sidx[rl][r1] = m0 + 64; }
  __syncthreads();

  // ---- softmax (redundant in both waves) + split angle computation ---------
  float e = 0.f;
  int   msel = 0;
  if (lane < kk) {
    e = expf(sval[rl][lane] - sval[rl][0]);   // rank 0 == max
    msel = sidx[rl][lane];
  }
  float ssum = e;
  #pragma unroll
  for (int off = 32; off; off >>= 1) ssum += __shfl_xor(ssum, off);

  const int h1 = (kk + 1) >> 1;
  const bool mine = sub ? (lane >= h1 && lane < kk) : (lane < h1);
  if (mine) {
    const float p = e / ssum;
    const float* xp = x_pos   + ((size_t)b * NP + msel) * 3;
    const float* sp = src_pos + ((size_t)b * NP + n) * 3;
    const float* L  = lrf     + ((size_t)b * NP + msel) * 9;  // row-major [y][x]
    float r0v = xp[0] - sp[0], r1v = xp[1] - sp[1], r2v = xp[2] - sp[2];
    float px = L[0]*r0v + L[3]*r1v + L[6]*r2v;   // lrf^T r
    float py = L[1]*r0v + L[4]*r1v + L[7]*r2v;
    float pz = L[2]*r0v + L[5]*r1v + L[8]*r2v;
    float alpha = atanf(py / px);
    if (px < 0.f) alpha += PI_F;
    if (isnan(alpha)) alpha = 0.f;
    float phi = atanf(pz / sqrtf(px*px + py*py));
    if (isnan(phi)) phi = 0.f;
    float sa, ca, sph, cph;
    sincosf(alpha, &sa, &ca);
    sincosf(phi, &sph, &cph);
    ang[rl][lane] = make_float4(p * ca, p * sa, p * cph, p * sph);
  }
  __syncthreads();

  // ---- gather + rotate-half + weighted sum (split over 2 waves) ------------
  const float* vbase = Vt + (size_t)bh * NP * DH;
  const bool useA = ((lane & 3) < 2);       // d%4 in {0,1} -> alpha else phi
  const bool odd  = (lane & 1);
  const int  ev   = lane & ~1;
  const float4* angp = ang[rl];
  const int jb = sub ? h1 : 0;
  const int je = sub ? kk : h1;
  float acc = 0.f;

  int j = jb;
  for (; j + 8 <= je; j += 8) {
    int4 ma = *(const int4*)&sidx[rl][j];
    int4 mb = *(const int4*)&sidx[rl][j + 4];
    int mloc[8] = { ma.x, ma.y, ma.z, ma.w, mb.x, mb.y, mb.z, mb.w };
    float2 vv[8];
    #pragma unroll
    for (int t = 0; t < 8; ++t)
      vv[t] = *(const float2*)(vbase + (size_t)mloc[t] * DH + ev);
    float4 aa[8];
    #pragma unroll
    for (int t = 0; t < 8; ++t) aa[t] = angp[j + t];
    #pragma unroll
    for (int t = 0; t < 8; ++t) {
      float vm  = odd ? vv[t].y :  vv[t].x;
      float dsc = odd ? vv[t].x : -vv[t].y;   // rotate-half pairs
      float pc  = useA ? aa[t].x : aa[t].z;
      float ps  = useA ? aa[t].y : aa[t].w;
      acc += vm * pc + dsc * ps;
    }
  }
  for (; j < je; ++j) {
    int m = sidx[rl][j];
    float2 v2 = *(const float2*)(vbase + (size_t)m * DH + ev);
    float vm  = odd ? v2.y :  v2.x;
    float dsc = odd ? v2.x : -v2.y;
    float4 a  = angp[j];
    float pc  = useA ? a.x : a.z;
    float ps  = useA ? a.y : a.w;
    acc += vm * pc + dsc * ps;
  }

  if (sub) part[rl][lane] = acc;
  __syncthreads();
  if (!sub) {
    const float tot = acc + part[rl][lane];
    const int c = (lane << 2) | h;   // channel = d*4 + h
    O[((size_t)b * DM + c) * NP + n] = tot;
  }
}

// ---------------------------------------------------------------------------
// Kernel D: final pointwise conv: out[b,co,n] = Wm @ O + bm  (same GEMM shape)
// ---------------------------------------------------------------------------
__global__ __launch_bounds__(256) void final_proj_kernel(
    const float* __restrict__ O, const float* __restrict__ Wm,
    const float* __restrict__ bm, float* __restrict__ out)
{
  const int tile = blockIdx.x;
  const int b    = blockIdx.y;
  const int tc = (tile >> 2) * 64;
  const int tp = (tile & 3) * 64;
  const float* X = O + (size_t)b * DM * NP;
  float* Y       = out + (size_t)b * DM * NP;

  __shared__ float Ws[2][32][64];
  __shared__ float Xs[2][32][64];
  const int tid = threadIdx.x;
  const int ty = tid >> 4, tx = tid & 15;
  const int c0 = tid >> 3;
  const int k4 = tid & 7;
  const int pX = tid & 15;
  const int kX = tid >> 4;

  float4 wA, wB, xA, xB;
  #define LOADF(K0)                                                            \
    wA = *(const float4*)&Wm[(size_t)(tc + c0)      * DM + (K0) + k4 * 4];     \
    wB = *(const float4*)&Wm[(size_t)(tc + c0 + 32) * DM + (K0) + k4 * 4];     \
    xA = *(const float4*)&X[(size_t)((K0) + kX)      * NP + tp + pX * 4];      \
    xB = *(const float4*)&X[(size_t)((K0) + kX + 16) * NP + tp + pX * 4];

  #define STOREF(BUF)                                                          \
    Ws[BUF][k4*4+0][c0] = wA.x; Ws[BUF][k4*4+1][c0] = wA.y;                    \
    Ws[BUF][k4*4+2][c0] = wA.z; Ws[BUF][k4*4+3][c0] = wA.w;                    \
    Ws[BUF][k4*4+0][c0+32] = wB.x; Ws[BUF][k4*4+1][c0+32] = wB.y;              \
    Ws[BUF][k4*4+2][c0+32] = wB.z; Ws[BUF][k4*4+3][c0+32] = wB.w;              \
    *(float4*)&Xs[BUF][kX][pX*4]      = xA;                                    \
    *(float4*)&Xs[BUF][kX+16][pX*4]   = xB;

  LOADF(0);
  STOREF(0);
  __syncthreads();

  float acc[4][4];
  #pragma unroll
  for (int i = 0; i < 4; ++i)
    #pragma unroll
    for (int j = 0; j < 4; ++j) acc[i][j] = 0.f;

  for (int ch = 0; ch < 8; ++ch) {
    const int cur = ch & 1;
    if (ch < 7) { LOADF((ch + 1) * 32); }
    #pragma unroll
    for (int kk = 0; kk < 32; ++kk) {
      float4 a = *(const float4*)&Ws[cur][kk][ty * 4];
      float4 xv = *(const float4*)&Xs[cur][kk][tx * 4];
      float av[4] = {a.x, a.y, a.z, a.w};
      float xvv[4] = {xv.x, xv.y, xv.z, xv.w};
      #pragma unroll
      for (int i = 0; i < 4; ++i)
        #pragma unroll
        for (int j = 0; j < 4; ++j) acc[i][j] += av[i] * xvv[j];
    }
    if (ch < 7) {
      STOREF(cur ^ 1);
      __syncthreads();
    }
  }

  #pragma unroll
  for (int i = 0; i < 4; ++i) {
    const int c = tc + ty * 4 + i;
    const float bb = bm[c];
    float4 o4;
    o4.x = acc[i][0] + bb; o4.y = acc[i][1] + bb;
    o4.z = acc[i][2] + bb; o4.w = acc[i][3] + bb;
    *(float4*)&Y[(size_t)c * NP + tp + tx * 4] = o4;
  }
  #undef LOADF
  #undef STOREF
}

// ---------------------------------------------------------------------------
extern "C" void kernel_launch(void* const* d_in, const int* in_sizes, int n_in,
                              void* d_out, int out_size, void* d_ws, size_t ws_size,
                              hipStream_t stream)
{
  const float* x       = (const float*)d_in[0];
  const float* source  = (const float*)d_in[1];
  const float* x_pos   = (const float*)d_in[2];
  const float* src_pos = (const float*)d_in[3];
  const float* lrf     = (const float*)d_in[4];
  const float* Wq = (const float*)d_in[5];
  const float* bq = (const float*)d_in[6];
  const float* Wk = (const float*)d_in[7];
  const float* bk = (const float*)d_in[8];
  const float* Wv = (const float*)d_in[9];
  const float* bv = (const float*)d_in[10];
  const float* Wm = (const float*)d_in[11];
  const float* bm = (const float*)d_in[12];
  const int* kptr = (const int*)d_in[13];
  float* out = (float*)d_out;

  // workspace layout (floats)
  float* ws = (float*)d_ws;
  float* Qt = ws;                         // [4][4][256][64] = 262144
  float* Kt = Qt + 262144;
  float* Vt = Kt + 262144;
  float* O  = Vt + 262144;                // [4][256][256]   = 262144
  // total: 4 MB

  qkv_proj_kernel<<<dim3(16, 3, 4), 256, 0, stream>>>(
      x, source, Wq, bq, Wk, bk, Wv, bv, Qt, Kt, Vt);
  attn_fused_kernel<<<dim3(2048), 256, 0, stream>>>(
      Qt, Kt, Vt, x_pos, src_pos, lrf, kptr, O);
  final_proj_kernel<<<dim3(16, 4), 256, 0, stream>>>(
      O, Wm, bm, out);
}

// Round 4
// 95.964 us; speedup vs baseline: 1.1471x; 1.1471x over previous
//
#include <hip/hip_runtime.h>
#include <math.h>

#define DM 256   // d_model
#define NP 256   // n == m == 256 points
#define NH 4     // heads
#define DH 64    // dim per head
#define PI_F 3.14159265358979323846f

typedef unsigned long long u64;
typedef __attribute__((ext_vector_type(2))) unsigned long long u64x2;

// ---------------------------------------------------------------------------
// Kernel A: Q/K/V pointwise conv (GEMM) + bias -> T[b][h][pt][d].
// 64x64 tile, 4x4 micro-tile, K-chunk 32, reg-staged double-buffered LDS.
// ---------------------------------------------------------------------------
__global__ __launch_bounds__(256) void qkv_proj_kernel(
    const float* __restrict__ x, const float* __restrict__ src,
    const float* __restrict__ Wq, const float* __restrict__ bq,
    const float* __restrict__ Wk, const float* __restrict__ bk,
    const float* __restrict__ Wv, const float* __restrict__ bv,
    float* __restrict__ Qt, float* __restrict__ Kt, float* __restrict__ Vt)
{
  const int tile = blockIdx.x;      // 16 tiles: 4x4 grid of 64x64
  const int mat  = blockIdx.y;      // 0=q, 1=k, 2=v
  const int b    = blockIdx.z;
  const int tc = (tile >> 2) * 64;
  const int tp = (tile & 3) * 64;
  const float* W    = (mat == 0) ? Wq : (mat == 1) ? Wk : Wv;
  const float* bias = (mat == 0) ? bq : (mat == 1) ? bk : bv;
  const float* X    = ((mat == 0) ? x : src) + (size_t)b * DM * NP;
  float* T          = ((mat == 0) ? Qt : (mat == 1) ? Kt : Vt) + (size_t)b * NH * NP * DH;

  __shared__ float Ws[2][32][64];
  __shared__ float Xs[2][32][64];
  const int tid = threadIdx.x;
  const int ty = tid >> 4, tx = tid & 15;
  const int c0 = tid >> 3;
  const int k4 = tid & 7;
  const int pX = tid & 15;
  const int kX = tid >> 4;

  float4 wA, wB, xA, xB;
  #define LOADQKV(K0)                                                          \
    wA = *(const float4*)&W[(size_t)(tc + c0)      * DM + (K0) + k4 * 4];      \
    wB = *(const float4*)&W[(size_t)(tc + c0 + 32) * DM + (K0) + k4 * 4];      \
    xA = *(const float4*)&X[(size_t)((K0) + kX)      * NP + tp + pX * 4];      \
    xB = *(const float4*)&X[(size_t)((K0) + kX + 16) * NP + tp + pX * 4];

  #define STOREQKV(BUF)                                                        \
    Ws[BUF][k4*4+0][c0] = wA.x; Ws[BUF][k4*4+1][c0] = wA.y;                    \
    Ws[BUF][k4*4+2][c0] = wA.z; Ws[BUF][k4*4+3][c0] = wA.w;                    \
    Ws[BUF][k4*4+0][c0+32] = wB.x; Ws[BUF][k4*4+1][c0+32] = wB.y;              \
    Ws[BUF][k4*4+2][c0+32] = wB.z; Ws[BUF][k4*4+3][c0+32] = wB.w;              \
    *(float4*)&Xs[BUF][kX][pX*4]      = xA;                                    \
    *(float4*)&Xs[BUF][kX+16][pX*4]   = xB;

  LOADQKV(0);
  STOREQKV(0);
  __syncthreads();

  float acc[4][4];
  #pragma unroll
  for (int i = 0; i < 4; ++i)
    #pragma unroll
    for (int j = 0; j < 4; ++j) acc[i][j] = 0.f;

  for (int ch = 0; ch < 8; ++ch) {
    const int cur = ch & 1;
    if (ch < 7) { LOADQKV((ch + 1) * 32); }
    #pragma unroll
    for (int kk = 0; kk < 32; ++kk) {
      float4 a = *(const float4*)&Ws[cur][kk][ty * 4];
      float4 xv = *(const float4*)&Xs[cur][kk][tx * 4];
      float av[4] = {a.x, a.y, a.z, a.w};
      float xvv[4] = {xv.x, xv.y, xv.z, xv.w};
      #pragma unroll
      for (int i = 0; i < 4; ++i)
        #pragma unroll
        for (int j = 0; j < 4; ++j) acc[i][j] += av[i] * xvv[j];
    }
    if (ch < 7) {
      STOREQKV(cur ^ 1);
      __syncthreads();
    }
  }

  #pragma unroll
  for (int i = 0; i < 4; ++i) {
    const int c = tc + ty * 4 + i;
    const float bb = bias[c];
    #pragma unroll
    for (int j = 0; j < 4; ++j) {
      const int p = tp + tx * 4 + j;
      T[((size_t)(c & 3) * NP + p) * DH + (c >> 2)] = acc[i][j] + bb;
    }
  }
  #undef LOADQKV
  #undef STOREQKV
}

// ---------------------------------------------------------------------------
// Kernel B (fused): one 256-thread block per (b,h,n) row; each of the 4 waves
// owns 64 candidate m's (ONE key/score per wave -> tiny register state).
// scores -> rank-by-counting top-k -> softmax -> rotary angles (1 thread per
// selected element, split by quarters) -> gather (quarter per wave) -> reduce.
// XCD-swizzled so each XCD's L2 keeps only 2 (b,h) K/V panels.
// ---------------------------------------------------------------------------
__global__ __launch_bounds__(256, 4) void attn_fused_kernel(
    const float* __restrict__ Qt, const float* __restrict__ Kt,
    const float* __restrict__ Vt,
    const float* __restrict__ x_pos, const float* __restrict__ src_pos,
    const float* __restrict__ lrf,
    const int* __restrict__ kptr,
    float* __restrict__ O)
{
  const int tid  = threadIdx.x;
  const int w    = tid >> 6;
  const int lane = tid & 63;
  const int bidx = blockIdx.x;
  const int row  = (bidx & 7) * 512 + (bidx >> 3);  // bijective XCD swizzle
  const int n    = row & (NP - 1);
  const int bh   = row >> 8;
  const int b    = bh >> 2;
  const int h    = bh & 3;

  int kk = *kptr;
  if (kk > 64) kk = 64;
  if (kk < 1) kk = 1;

  __shared__ float qs[DH];
  __shared__ alignas(16) u64 keys[NP];
  __shared__ float sval[64];
  __shared__ int   sidx[64];
  __shared__ float4 ang[64];
  __shared__ float part[4][64];

  if (tid < DH) qs[tid] = Qt[(size_t)row * DH + tid];
  __syncthreads();

  // ---- score for m = w*64 + lane (one per thread) --------------------------
  const float* kbase = Kt + (size_t)bh * NP * DH;
  const int m0 = (w << 6) | lane;
  const float4* q4 = (const float4*)qs;
  const float4* kp = (const float4*)(kbase + (size_t)m0 * DH);
  float s = 0.f;
  #pragma unroll
  for (int dd = 0; dd < 16; ++dd) {
    float4 qv = q4[dd], a = kp[dd];
    s += a.x*qv.x + a.y*qv.y + a.z*qv.z + a.w*qv.w;
  }
  s *= 0.125f;

  // sortable key: value<<32 | (255-m)  (distinct keys; ties -> smaller m)
  unsigned int bits = __float_as_uint(s);
  bits = (bits & 0x80000000u) ? ~bits : (bits | 0x80000000u);
  const u64 key = ((u64)bits << 32) | (unsigned int)(255 - m0);
  keys[m0] = key;
  __syncthreads();

  // ---- rank by counting (broadcast b128 LDS reads, pure VALU) --------------
  int rank = 0;
  #pragma unroll 8
  for (int j = 0; j < NP; j += 2) {
    u64x2 kp2 = *(const u64x2*)&keys[j];
    rank += (kp2.x > key);
    rank += (kp2.y > key);
  }
  if (rank < kk) { sval[rank] = s; sidx[rank] = m0; }
  __syncthreads();

  // ---- softmax (redundant per wave, in-register) ---------------------------
  float e = 0.f;
  if (lane < kk) e = expf(sval[lane] - sval[0]);   // rank 0 == max
  float ssum = e;
  #pragma unroll
  for (int off = 32; off; off >>= 1) ssum += __shfl_xor(ssum, off);

  // this wave's quarter of the selected set
  const int base = (kk * w) >> 2;
  const int end  = (kk * (w + 1)) >> 2;
  const int cnt  = end - base;                     // <= 16

  // ---- angles: one thread per selected element in this quarter -------------
  const int jj = (base + lane) & 63;
  const float ej = __shfl(e, jj);                  // executed by all lanes
  if (lane < cnt) {
    const int j = base + lane;
    const int msel = sidx[j];
    const float p = ej / ssum;
    const float* xp = x_pos   + ((size_t)b * NP + msel) * 3;
    const float* sp = src_pos + ((size_t)b * NP + n) * 3;
    const float* L  = lrf     + ((size_t)b * NP + msel) * 9;  // row-major [y][x]
    float r0 = xp[0] - sp[0], r1 = xp[1] - sp[1], r2 = xp[2] - sp[2];
    float px = L[0]*r0 + L[3]*r1 + L[6]*r2;        // lrf^T r
    float py = L[1]*r0 + L[4]*r1 + L[7]*r2;
    float pz = L[2]*r0 + L[5]*r1 + L[8]*r2;
    float alpha = atanf(py / px);
    if (px < 0.f) alpha += PI_F;
    if (isnan(alpha)) alpha = 0.f;
    float phi = atanf(pz / sqrtf(px*px + py*py));
    if (isnan(phi)) phi = 0.f;
    float sa, ca, sph, cph;
    sincosf(alpha, &sa, &ca);
    sincosf(phi, &sph, &cph);
    ang[j] = make_float4(p * ca, p * sa, p * cph, p * sph);
  }
  __syncthreads();

  // ---- gather + rotate-half + weighted sum (quarter per wave, 4-deep) ------
  const float* vbase = Vt + (size_t)bh * NP * DH;
  const bool useA = ((lane & 3) < 2);   // d%4 in {0,1} -> alpha else phi
  const bool odd  = (lane & 1);
  const int  ev   = lane & ~1;
  float acc = 0.f;

  int j = base;
  for (; j + 4 <= end; j += 4) {
    int mloc[4]; float2 vv[4]; float4 aa[4];
    #pragma unroll
    for (int t = 0; t < 4; ++t) mloc[t] = sidx[j + t];
    #pragma unroll
    for (int t = 0; t < 4; ++t) {
      vv[t] = *(const float2*)(vbase + (size_t)mloc[t] * DH + ev);
      aa[t] = ang[j + t];
    }
    #pragma unroll
    for (int t = 0; t < 4; ++t) {
      float vm  = odd ? vv[t].y :  vv[t].x;
      float dsc = odd ? vv[t].x : -vv[t].y;       // rotate-half pairs
      float pc  = useA ? aa[t].x : aa[t].z;
      float ps  = useA ? aa[t].y : aa[t].w;
      acc += vm * pc + dsc * ps;
    }
  }
  for (; j < end; ++j) {
    int m = sidx[j];
    float2 v2 = *(const float2*)(vbase + (size_t)m * DH + ev);
    float vm  = odd ? v2.y :  v2.x;
    float dsc = odd ? v2.x : -v2.y;
    float4 a  = ang[j];
    float pc  = useA ? a.x : a.z;
    float ps  = useA ? a.y : a.w;
    acc += vm * pc + dsc * ps;
  }

  part[w][lane] = acc;
  __syncthreads();
  if (tid < DH) {
    const float tot = part[0][tid] + part[1][tid] + part[2][tid] + part[3][tid];
    const int c = (tid << 2) | h;   // channel = d*4 + h
    O[((size_t)b * DM + c) * NP + n] = tot;
  }
}

// ---------------------------------------------------------------------------
// Kernel D: final pointwise conv: out[b,co,n] = Wm @ O + bm
// ---------------------------------------------------------------------------
__global__ __launch_bounds__(256) void final_proj_kernel(
    const float* __restrict__ O, const float* __restrict__ Wm,
    const float* __restrict__ bm, float* __restrict__ out)
{
  const int tile = blockIdx.x;
  const int b    = blockIdx.y;
  const int tc = (tile >> 2) * 64;
  const int tp = (tile & 3) * 64;
  const float* X = O + (size_t)b * DM * NP;
  float* Y       = out + (size_t)b * DM * NP;

  __shared__ float Ws[2][32][64];
  __shared__ float Xs[2][32][64];
  const int tid = threadIdx.x;
  const int ty = tid >> 4, tx = tid & 15;
  const int c0 = tid >> 3;
  const int k4 = tid & 7;
  const int pX = tid & 15;
  const int kX = tid >> 4;

  float4 wA, wB, xA, xB;
  #define LOADF(K0)                                                            \
    wA = *(const float4*)&Wm[(size_t)(tc + c0)      * DM + (K0) + k4 * 4];     \
    wB = *(const float4*)&Wm[(size_t)(tc + c0 + 32) * DM + (K0) + k4 * 4];     \
    xA = *(const float4*)&X[(size_t)((K0) + kX)      * NP + tp + pX * 4];      \
    xB = *(const float4*)&X[(size_t)((K0) + kX + 16) * NP + tp + pX * 4];

  #define STOREF(BUF)                                                          \
    Ws[BUF][k4*4+0][c0] = wA.x; Ws[BUF][k4*4+1][c0] = wA.y;                    \
    Ws[BUF][k4*4+2][c0] = wA.z; Ws[BUF][k4*4+3][c0] = wA.w;                    \
    Ws[BUF][k4*4+0][c0+32] = wB.x; Ws[BUF][k4*4+1][c0+32] = wB.y;              \
    Ws[BUF][k4*4+2][c0+32] = wB.z; Ws[BUF][k4*4+3][c0+32] = wB.w;              \
    *(float4*)&Xs[BUF][kX][pX*4]      = xA;                                    \
    *(float4*)&Xs[BUF][kX+16][pX*4]   = xB;

  LOADF(0);
  STOREF(0);
  __syncthreads();

  float acc[4][4];
  #pragma unroll
  for (int i = 0; i < 4; ++i)
    #pragma unroll
    for (int j = 0; j < 4; ++j) acc[i][j] = 0.f;

  for (int ch = 0; ch < 8; ++ch) {
    const int cur = ch & 1;
    if (ch < 7) { LOADF((ch + 1) * 32); }
    #pragma unroll
    for (int kk = 0; kk < 32; ++kk) {
      float4 a = *(const float4*)&Ws[cur][kk][ty * 4];
      float4 xv = *(const float4*)&Xs[cur][kk][tx * 4];
      float av[4] = {a.x, a.y, a.z, a.w};
      float xvv[4] = {xv.x, xv.y, xv.z, xv.w};
      #pragma unroll
      for (int i = 0; i < 4; ++i)
        #pragma unroll
        for (int j = 0; j < 4; ++j) acc[i][j] += av[i] * xvv[j];
    }
    if (ch < 7) {
      STOREF(cur ^ 1);
      __syncthreads();
    }
  }

  #pragma unroll
  for (int i = 0; i < 4; ++i) {
    const int c = tc + ty * 4 + i;
    const float bb = bm[c];
    float4 o4;
    o4.x = acc[i][0] + bb; o4.y = acc[i][1] + bb;
    o4.z = acc[i][2] + bb; o4.w = acc[i][3] + bb;
    *(float4*)&Y[(size_t)c * NP + tp + tx * 4] = o4;
  }
  #undef LOADF
  #undef STOREF
}

// ---------------------------------------------------------------------------
extern "C" void kernel_launch(void* const* d_in, const int* in_sizes, int n_in,
                              void* d_out, int out_size, void* d_ws, size_t ws_size,
                              hipStream_t stream)
{
  const float* x       = (const float*)d_in[0];
  const float* source  = (const float*)d_in[1];
  const float* x_pos   = (const float*)d_in[2];
  const float* src_pos = (const float*)d_in[3];
  const float* lrf     = (const float*)d_in[4];
  const float* Wq = (const float*)d_in[5];
  const float* bq = (const float*)d_in[6];
  const float* Wk = (const float*)d_in[7];
  const float* bk = (const float*)d_in[8];
  const float* Wv = (const float*)d_in[9];
  const float* bv = (const float*)d_in[10];
  const float* Wm = (const float*)d_in[11];
  const float* bm = (const float*)d_in[12];
  const int* kptr = (const int*)d_in[13];
  float* out = (float*)d_out;

  // workspace layout (floats)
  float* ws = (float*)d_ws;
  float* Qt = ws;                         // [4][4][256][64] = 262144
  float* Kt = Qt + 262144;
  float* Vt = Kt + 262144;
  float* O  = Vt + 262144;                // [4][256][256]   = 262144
  // total: 4 MB

  qkv_proj_kernel<<<dim3(16, 3, 4), 256, 0, stream>>>(
      x, source, Wq, bq, Wk, bk, Wv, bv, Qt, Kt, Vt);
  attn_fused_kernel<<<dim3(4096), 256, 0, stream>>>(
      Qt, Kt, Vt, x_pos, src_pos, lrf, kptr, O);
  final_proj_kernel<<<dim3(16, 4), 256, 0, stream>>>(
      O, Wm, bm, out);
}

// Round 5
// 76.863 us; speedup vs baseline: 1.4322x; 1.2485x over previous
//
#include <hip/hip_runtime.h>
#include <math.h>

#define DM 256   // d_model
#define NP 256   // n == m == 256 points
#define NH 4     // heads
#define DH 64    // dim per head
#define PI_F 3.14159265358979323846f

typedef unsigned long long u64;
typedef unsigned int u32;
typedef __attribute__((ext_vector_type(2))) unsigned long long u64x2;

// ---------------------------------------------------------------------------
// Kernel A: Q/K/V pointwise conv (GEMM) + bias -> T[b][h][pt][d].
// ---------------------------------------------------------------------------
__global__ __launch_bounds__(256) void qkv_proj_kernel(
    const float* __restrict__ x, const float* __restrict__ src,
    const float* __restrict__ Wq, const float* __restrict__ bq,
    const float* __restrict__ Wk, const float* __restrict__ bk,
    const float* __restrict__ Wv, const float* __restrict__ bv,
    float* __restrict__ Qt, float* __restrict__ Kt, float* __restrict__ Vt)
{
  const int tile = blockIdx.x;      // 16 tiles: 4x4 grid of 64x64
  const int mat  = blockIdx.y;      // 0=q, 1=k, 2=v
  const int b    = blockIdx.z;
  const int tc = (tile >> 2) * 64;
  const int tp = (tile & 3) * 64;
  const float* W    = (mat == 0) ? Wq : (mat == 1) ? Wk : Wv;
  const float* bias = (mat == 0) ? bq : (mat == 1) ? bk : bv;
  const float* X    = ((mat == 0) ? x : src) + (size_t)b * DM * NP;
  float* T          = ((mat == 0) ? Qt : (mat == 1) ? Kt : Vt) + (size_t)b * NH * NP * DH;

  __shared__ float Ws[2][32][64];
  __shared__ float Xs[2][32][64];
  const int tid = threadIdx.x;
  const int ty = tid >> 4, tx = tid & 15;
  const int c0 = tid >> 3;
  const int k4 = tid & 7;
  const int pX = tid & 15;
  const int kX = tid >> 4;

  float4 wA, wB, xA, xB;
  #define LOADQKV(K0)                                                          \
    wA = *(const float4*)&W[(size_t)(tc + c0)      * DM + (K0) + k4 * 4];      \
    wB = *(const float4*)&W[(size_t)(tc + c0 + 32) * DM + (K0) + k4 * 4];      \
    xA = *(const float4*)&X[(size_t)((K0) + kX)      * NP + tp + pX * 4];      \
    xB = *(const float4*)&X[(size_t)((K0) + kX + 16) * NP + tp + pX * 4];

  #define STOREQKV(BUF)                                                        \
    Ws[BUF][k4*4+0][c0] = wA.x; Ws[BUF][k4*4+1][c0] = wA.y;                    \
    Ws[BUF][k4*4+2][c0] = wA.z; Ws[BUF][k4*4+3][c0] = wA.w;                    \
    Ws[BUF][k4*4+0][c0+32] = wB.x; Ws[BUF][k4*4+1][c0+32] = wB.y;              \
    Ws[BUF][k4*4+2][c0+32] = wB.z; Ws[BUF][k4*4+3][c0+32] = wB.w;              \
    *(float4*)&Xs[BUF][kX][pX*4]      = xA;                                    \
    *(float4*)&Xs[BUF][kX+16][pX*4]   = xB;

  LOADQKV(0);
  STOREQKV(0);
  __syncthreads();

  float acc[4][4];
  #pragma unroll
  for (int i = 0; i < 4; ++i)
    #pragma unroll
    for (int j = 0; j < 4; ++j) acc[i][j] = 0.f;

  for (int ch = 0; ch < 8; ++ch) {
    const int cur = ch & 1;
    if (ch < 7) { LOADQKV((ch + 1) * 32); }
    #pragma unroll
    for (int kk = 0; kk < 32; ++kk) {
      float4 a = *(const float4*)&Ws[cur][kk][ty * 4];
      float4 xv = *(const float4*)&Xs[cur][kk][tx * 4];
      float av[4] = {a.x, a.y, a.z, a.w};
      float xvv[4] = {xv.x, xv.y, xv.z, xv.w};
      #pragma unroll
      for (int i = 0; i < 4; ++i)
        #pragma unroll
        for (int j = 0; j < 4; ++j) acc[i][j] += av[i] * xvv[j];
    }
    if (ch < 7) {
      STOREQKV(cur ^ 1);
      __syncthreads();
    }
  }

  #pragma unroll
  for (int i = 0; i < 4; ++i) {
    const int c = tc + ty * 4 + i;
    const float bb = bias[c];
    #pragma unroll
    for (int j = 0; j < 4; ++j) {
      const int p = tp + tx * 4 + j;
      T[((size_t)(c & 3) * NP + p) * DH + (c >> 2)] = acc[i][j] + bb;
    }
  }
  #undef LOADQKV
  #undef STOREQKV
}

// ---------------------------------------------------------------------------
// Kernel B (fused): one 256-thread block per (b,h,n) row; thread tid owns
// candidate m = tid. scores -> EXACT histogram top-k select (8-bit bucket
// histogram + suffix scan; boundary bucket resolved by exact u64 rank-count
// among candidates only) -> softmax -> rotary angles -> gather -> reduce.
// ---------------------------------------------------------------------------
__global__ __launch_bounds__(256) void attn_fused_kernel(
    const float* __restrict__ Qt, const float* __restrict__ Kt,
    const float* __restrict__ Vt,
    const float* __restrict__ x_pos, const float* __restrict__ src_pos,
    const float* __restrict__ lrf,
    const int* __restrict__ kptr,
    float* __restrict__ O)
{
  const int tid  = threadIdx.x;
  const int w    = tid >> 6;
  const int lane = tid & 63;
  const int bidx = blockIdx.x;
  const int row  = (bidx & 7) * 512 + (bidx >> 3);  // bijective XCD swizzle
  const int n    = row & (NP - 1);
  const int bh   = row >> 8;
  const int b    = bh >> 2;
  const int h    = bh & 3;

  int kk = *kptr;
  if (kk > 64) kk = 64;
  if (kk < 1) kk = 1;

  __shared__ float qs[DH];
  __shared__ int   hist[256];
  __shared__ int   csum[256];
  __shared__ alignas(16) u64 cu64[256];
  __shared__ float cs[256];
  __shared__ int   cm[256];
  __shared__ float sval[64];
  __shared__ int   sidx[64];
  __shared__ float4 ang[64];
  __shared__ float part[4][64];
  __shared__ int   cnt, cand_cnt;
  __shared__ u32   smax;

  if (tid < DH) qs[tid] = Qt[(size_t)row * DH + tid];
  hist[tid] = 0;
  if (tid == 0) { cnt = 0; cand_cnt = 0; smax = 0u; }
  __syncthreads();

  // ---- score for m = tid ---------------------------------------------------
  const float* kbase = Kt + (size_t)bh * NP * DH;
  const int m0 = tid;
  const float4* q4 = (const float4*)qs;
  const float4* kp = (const float4*)(kbase + (size_t)m0 * DH);
  float s = 0.f;
  #pragma unroll
  for (int dd = 0; dd < 16; ++dd) {
    float4 qv = q4[dd], a = kp[dd];
    s += a.x*qv.x + a.y*qv.y + a.z*qv.z + a.w*qv.w;
  }
  s *= 0.125f;

  // sortable u32 (full precision); u64 key adds index tiebreak (smaller m wins)
  u32 u = __float_as_uint(s);
  u = (u & 0x80000000u) ? ~u : (u | 0x80000000u);
  const u64 key = ((u64)u << 32) | (u32)(255 - m0);
  const int b1 = u >> 24;
  atomicMax(&smax, u);
  atomicAdd(&hist[b1], 1);
  __syncthreads();

  // ---- suffix scan: csum[b] = #keys in buckets strictly greater than b -----
  if (w == 0) {
    const int h0 = hist[4*lane+0], h1 = hist[4*lane+1];
    const int h2 = hist[4*lane+2], h3 = hist[4*lane+3];
    int S = h0 + h1 + h2 + h3;                 // inclusive suffix over lanes
    #pragma unroll
    for (int off = 1; off < 64; off <<= 1) {
      int t = __shfl_down(S, off);
      if (lane + off < 64) S += t;
    }
    int Snext = __shfl_down(S, 1);
    if (lane == 63) Snext = 0;
    csum[4*lane+3] = Snext;
    csum[4*lane+2] = Snext + h3;
    csum[4*lane+1] = Snext + h3 + h2;
    csum[4*lane+0] = Snext + h3 + h2 + h1;
  }
  __syncthreads();

  // ---- classify: whole-bucket-in / boundary-bucket candidate ---------------
  const int c_gt = csum[b1];
  const int nb   = hist[b1];
  if (c_gt + nb <= kk) {                       // definitely in top-k
    const int slot = atomicAdd(&cnt, 1);
    sval[slot] = s; sidx[slot] = m0;
  } else if (c_gt < kk) {                      // boundary bucket: candidate
    const int ci = atomicAdd(&cand_cnt, 1);
    cu64[ci] = key; cs[ci] = s; cm[ci] = m0;
  }
  __syncthreads();
  const int C  = cnt;
  const int nc = cand_cnt;
  __syncthreads();

  // ---- exact rank among boundary candidates only ---------------------------
  const int r = kk - C;                        // how many more to take
  if (tid < nc) {
    const u64 mk = cu64[tid];
    int rk = 0;
    int j2 = 0;
    for (; j2 + 2 <= nc; j2 += 2) {
      u64x2 kp2 = *(const u64x2*)&cu64[j2];
      rk += (kp2.x > mk);
      rk += (kp2.y > mk);
    }
    for (; j2 < nc; ++j2) rk += (cu64[j2] > mk);
    if (rk < r) {
      const int slot = atomicAdd(&cnt, 1);
      sval[slot] = cs[tid]; sidx[slot] = cm[tid];
    }
  }
  __syncthreads();

  // ---- softmax (redundant per wave, in-register) ---------------------------
  const u32 um = smax;
  const float vmax = __uint_as_float((um & 0x80000000u) ? (um & 0x7fffffffu) : ~um);
  float e = 0.f;
  if (lane < kk) e = expf(sval[lane] - vmax);
  float ssum = e;
  #pragma unroll
  for (int off = 32; off; off >>= 1) ssum += __shfl_xor(ssum, off);

  // this wave's quarter of the selected set
  const int base = (kk * w) >> 2;
  const int end  = (kk * (w + 1)) >> 2;
  const int cnt4 = end - base;                 // <= 16

  // ---- angles: one thread per selected element in this quarter -------------
  const int jj = (base + lane) & 63;
  const float ej = __shfl(e, jj);              // executed by all lanes
  if (lane < cnt4) {
    const int j = base + lane;
    const int msel = sidx[j];
    const float p = ej / ssum;
    const float* xp = x_pos   + ((size_t)b * NP + msel) * 3;
    const float* sp = src_pos + ((size_t)b * NP + n) * 3;
    const float* L  = lrf     + ((size_t)b * NP + msel) * 9;  // row-major [y][x]
    float r0 = xp[0] - sp[0], r1 = xp[1] - sp[1], r2 = xp[2] - sp[2];
    float px = L[0]*r0 + L[3]*r1 + L[6]*r2;    // lrf^T r
    float py = L[1]*r0 + L[4]*r1 + L[7]*r2;
    float pz = L[2]*r0 + L[5]*r1 + L[8]*r2;
    float alpha = atanf(py / px);
    if (px < 0.f) alpha += PI_F;
    if (isnan(alpha)) alpha = 0.f;
    float phi = atanf(pz / sqrtf(px*px + py*py));
    if (isnan(phi)) phi = 0.f;
    float sa, ca, sph, cph;
    sincosf(alpha, &sa, &ca);
    sincosf(phi, &sph, &cph);
    ang[j] = make_float4(p * ca, p * sa, p * cph, p * sph);
  }
  __syncthreads();

  // ---- gather + rotate-half + weighted sum (named scalars, no arrays) ------
  const float* vbase = Vt + (size_t)bh * NP * DH;
  const bool useA = ((lane & 3) < 2);          // d%4 in {0,1} -> alpha else phi
  const bool odd  = (lane & 1);
  const int  ev   = lane & ~1;
  float acc = 0.f;

  int j = base;
  for (; j + 4 <= end; j += 4) {
    const int ma = sidx[j], mb = sidx[j+1], mc = sidx[j+2], md = sidx[j+3];
    const float2 va = *(const float2*)(vbase + (size_t)ma * DH + ev);
    const float2 vb = *(const float2*)(vbase + (size_t)mb * DH + ev);
    const float2 vc = *(const float2*)(vbase + (size_t)mc * DH + ev);
    const float2 vd = *(const float2*)(vbase + (size_t)md * DH + ev);
    const float4 Aa = ang[j], Ab = ang[j+1], Ac = ang[j+2], Ad = ang[j+3];
    float vm, dsc, pc, ps;
    vm = odd ? va.y : va.x;  dsc = odd ? va.x : -va.y;
    pc = useA ? Aa.x : Aa.z; ps  = useA ? Aa.y : Aa.w;
    acc += vm * pc + dsc * ps;
    vm = odd ? vb.y : vb.x;  dsc = odd ? vb.x : -vb.y;
    pc = useA ? Ab.x : Ab.z; ps  = useA ? Ab.y : Ab.w;
    acc += vm * pc + dsc * ps;
    vm = odd ? vc.y : vc.x;  dsc = odd ? vc.x : -vc.y;
    pc = useA ? Ac.x : Ac.z; ps  = useA ? Ac.y : Ac.w;
    acc += vm * pc + dsc * ps;
    vm = odd ? vd.y : vd.x;  dsc = odd ? vd.x : -vd.y;
    pc = useA ? Ad.x : Ad.z; ps  = useA ? Ad.y : Ad.w;
    acc += vm * pc + dsc * ps;
  }
  for (; j < end; ++j) {
    const int m = sidx[j];
    const float2 v2 = *(const float2*)(vbase + (size_t)m * DH + ev);
    const float4 a  = ang[j];
    const float vm  = odd ? v2.y :  v2.x;
    const float dsc = odd ? v2.x : -v2.y;
    const float pc  = useA ? a.x : a.z;
    const float ps  = useA ? a.y : a.w;
    acc += vm * pc + dsc * ps;
  }

  part[w][lane] = acc;
  __syncthreads();
  if (tid < DH) {
    const float tot = part[0][tid] + part[1][tid] + part[2][tid] + part[3][tid];
    const int c = (tid << 2) | h;              // channel = d*4 + h
    O[((size_t)b * DM + c) * NP + n] = tot;
  }
}

// ---------------------------------------------------------------------------
// Kernel D: final pointwise conv: out[b,co,n] = Wm @ O + bm
// ---------------------------------------------------------------------------
__global__ __launch_bounds__(256) void final_proj_kernel(
    const float* __restrict__ O, const float* __restrict__ Wm,
    const float* __restrict__ bm, float* __restrict__ out)
{
  const int tile = blockIdx.x;
  const int b    = blockIdx.y;
  const int tc = (tile >> 2) * 64;
  const int tp = (tile & 3) * 64;
  const float* X = O + (size_t)b * DM * NP;
  float* Y       = out + (size_t)b * DM * NP;

  __shared__ float Ws[2][32][64];
  __shared__ float Xs[2][32][64];
  const int tid = threadIdx.x;
  const int ty = tid >> 4, tx = tid & 15;
  const int c0 = tid >> 3;
  const int k4 = tid & 7;
  const int pX = tid & 15;
  const int kX = tid >> 4;

  float4 wA, wB, xA, xB;
  #define LOADF(K0)                                                            \
    wA = *(const float4*)&Wm[(size_t)(tc + c0)      * DM + (K0) + k4 * 4];     \
    wB = *(const float4*)&Wm[(size_t)(tc + c0 + 32) * DM + (K0) + k4 * 4];     \
    xA = *(const float4*)&X[(size_t)((K0) + kX)      * NP + tp + pX * 4];      \
    xB = *(const float4*)&X[(size_t)((K0) + kX + 16) * NP + tp + pX * 4];

  #define STOREF(BUF)                                                          \
    Ws[BUF][k4*4+0][c0] = wA.x; Ws[BUF][k4*4+1][c0] = wA.y;                    \
    Ws[BUF][k4*4+2][c0] = wA.z; Ws[BUF][k4*4+3][c0] = wA.w;                    \
    Ws[BUF][k4*4+0][c0+32] = wB.x; Ws[BUF][k4*4+1][c0+32] = wB.y;              \
    Ws[BUF][k4*4+2][c0+32] = wB.z; Ws[BUF][k4*4+3][c0+32] = wB.w;              \
    *(float4*)&Xs[BUF][kX][pX*4]      = xA;                                    \
    *(float4*)&Xs[BUF][kX+16][pX*4]   = xB;

  LOADF(0);
  STOREF(0);
  __syncthreads();

  float acc[4][4];
  #pragma unroll
  for (int i = 0; i < 4; ++i)
    #pragma unroll
    for (int j = 0; j < 4; ++j) acc[i][j] = 0.f;

  for (int ch = 0; ch < 8; ++ch) {
    const int cur = ch & 1;
    if (ch < 7) { LOADF((ch + 1) * 32); }
    #pragma unroll
    for (int kk = 0; kk < 32; ++kk) {
      float4 a = *(const float4*)&Ws[cur][kk][ty * 4];
      float4 xv = *(const float4*)&Xs[cur][kk][tx * 4];
      float av[4] = {a.x, a.y, a.z, a.w};
      float xvv[4] = {xv.x, xv.y, xv.z, xv.w};
      #pragma unroll
      for (int i = 0; i < 4; ++i)
        #pragma unroll
        for (int j = 0; j < 4; ++j) acc[i][j] += av[i] * xvv[j];
    }
    if (ch < 7) {
      STOREF(cur ^ 1);
      __syncthreads();
    }
  }

  #pragma unroll
  for (int i = 0; i < 4; ++i) {
    const int c = tc + ty * 4 + i;
    const float bb = bm[c];
    float4 o4;
    o4.x = acc[i][0] + bb; o4.y = acc[i][1] + bb;
    o4.z = acc[i][2] + bb; o4.w = acc[i][3] + bb;
    *(float4*)&Y[(size_t)c * NP + tp + tx * 4] = o4;
  }
  #undef LOADF
  #undef STOREF
}

// ---------------------------------------------------------------------------
extern "C" void kernel_launch(void* const* d_in, const int* in_sizes, int n_in,
                              void* d_out, int out_size, void* d_ws, size_t ws_size,
                              hipStream_t stream)
{
  const float* x       = (const float*)d_in[0];
  const float* source  = (const float*)d_in[1];
  const float* x_pos   = (const float*)d_in[2];
  const float* src_pos = (const float*)d_in[3];
  const float* lrf     = (const float*)d_in[4];
  const float* Wq = (const float*)d_in[5];
  const float* bq = (const float*)d_in[6];
  const float* Wk = (const float*)d_in[7];
  const float* bk = (const float*)d_in[8];
  const float* Wv = (const float*)d_in[9];
  const float* bv = (const float*)d_in[10];
  const float* Wm = (const float*)d_in[11];
  const float* bm = (const float*)d_in[12];
  const int* kptr = (const int*)d_in[13];
  float* out = (float*)d_out;

  // workspace layout (floats)
  float* ws = (float*)d_ws;
  float* Qt = ws;                         // [4][4][256][64] = 262144
  float* Kt = Qt + 262144;
  float* Vt = Kt + 262144;
  float* O  = Vt + 262144;                // [4][256][256]   = 262144
  // total: 4 MB

  qkv_proj_kernel<<<dim3(16, 3, 4), 256, 0, stream>>>(
      x, source, Wq, bq, Wk, bk, Wv, bv, Qt, Kt, Vt);
  attn_fused_kernel<<<dim3(4096), 256, 0, stream>>>(
      Qt, Kt, Vt, x_pos, src_pos, lrf, kptr, O);
  final_proj_kernel<<<dim3(16, 4), 256, 0, stream>>>(
      O, Wm, bm, out);
}

// Round 6
// 73.883 us; speedup vs baseline: 1.4900x; 1.0403x over previous
//
#include <hip/hip_runtime.h>
#include <math.h>

#define DM 256   // d_model
#define NP 256   // n == m == 256 points
#define NH 4     // heads
#define DH 64    // dim per head

typedef unsigned long long u64;
typedef unsigned int u32;

static __device__ __forceinline__ u64 shfl_xor_u64(u64 x, int m) {
  u32 lo = (u32)x, hi = (u32)(x >> 32);
  lo = __shfl_xor(lo, m);
  hi = __shfl_xor(hi, m);
  return ((u64)hi << 32) | lo;
}

// ---------------------------------------------------------------------------
// Kernel A: Q/K/V pointwise conv (GEMM) + bias -> T[b][h][pt][d].
// ---------------------------------------------------------------------------
__global__ __launch_bounds__(256) void qkv_proj_kernel(
    const float* __restrict__ x, const float* __restrict__ src,
    const float* __restrict__ Wq, const float* __restrict__ bq,
    const float* __restrict__ Wk, const float* __restrict__ bk,
    const float* __restrict__ Wv, const float* __restrict__ bv,
    float* __restrict__ Qt, float* __restrict__ Kt, float* __restrict__ Vt)
{
  const int tile = blockIdx.x;      // 16 tiles: 4x4 grid of 64x64
  const int mat  = blockIdx.y;      // 0=q, 1=k, 2=v
  const int b    = blockIdx.z;
  const int tc = (tile >> 2) * 64;
  const int tp = (tile & 3) * 64;
  const float* W    = (mat == 0) ? Wq : (mat == 1) ? Wk : Wv;
  const float* bias = (mat == 0) ? bq : (mat == 1) ? bk : bv;
  const float* X    = ((mat == 0) ? x : src) + (size_t)b * DM * NP;
  float* T          = ((mat == 0) ? Qt : (mat == 1) ? Kt : Vt) + (size_t)b * NH * NP * DH;

  __shared__ float Ws[2][32][64];
  __shared__ float Xs[2][32][64];
  const int tid = threadIdx.x;
  const int ty = tid >> 4, tx = tid & 15;
  const int c0 = tid >> 3;
  const int k4 = tid & 7;
  const int pX = tid & 15;
  const int kX = tid >> 4;

  float4 wA, wB, xA, xB;
  #define LOADQKV(K0)                                                          \
    wA = *(const float4*)&W[(size_t)(tc + c0)      * DM + (K0) + k4 * 4];      \
    wB = *(const float4*)&W[(size_t)(tc + c0 + 32) * DM + (K0) + k4 * 4];      \
    xA = *(const float4*)&X[(size_t)((K0) + kX)      * NP + tp + pX * 4];      \
    xB = *(const float4*)&X[(size_t)((K0) + kX + 16) * NP + tp + pX * 4];

  #define STOREQKV(BUF)                                                        \
    Ws[BUF][k4*4+0][c0] = wA.x; Ws[BUF][k4*4+1][c0] = wA.y;                    \
    Ws[BUF][k4*4+2][c0] = wA.z; Ws[BUF][k4*4+3][c0] = wA.w;                    \
    Ws[BUF][k4*4+0][c0+32] = wB.x; Ws[BUF][k4*4+1][c0+32] = wB.y;              \
    Ws[BUF][k4*4+2][c0+32] = wB.z; Ws[BUF][k4*4+3][c0+32] = wB.w;              \
    *(float4*)&Xs[BUF][kX][pX*4]      = xA;                                    \
    *(float4*)&Xs[BUF][kX+16][pX*4]   = xB;

  LOADQKV(0);
  STOREQKV(0);
  __syncthreads();

  float acc[4][4];
  #pragma unroll
  for (int i = 0; i < 4; ++i)
    #pragma unroll
    for (int j = 0; j < 4; ++j) acc[i][j] = 0.f;

  for (int ch = 0; ch < 8; ++ch) {
    const int cur = ch & 1;
    if (ch < 7) { LOADQKV((ch + 1) * 32); }
    #pragma unroll
    for (int kk = 0; kk < 32; ++kk) {
      float4 a = *(const float4*)&Ws[cur][kk][ty * 4];
      float4 xv = *(const float4*)&Xs[cur][kk][tx * 4];
      float av[4] = {a.x, a.y, a.z, a.w};
      float xvv[4] = {xv.x, xv.y, xv.z, xv.w};
      #pragma unroll
      for (int i = 0; i < 4; ++i)
        #pragma unroll
        for (int j = 0; j < 4; ++j) acc[i][j] += av[i] * xvv[j];
    }
    if (ch < 7) {
      STOREQKV(cur ^ 1);
      __syncthreads();
    }
  }

  #pragma unroll
  for (int i = 0; i < 4; ++i) {
    const int c = tc + ty * 4 + i;
    const float bb = bias[c];
    #pragma unroll
    for (int j = 0; j < 4; ++j) {
      const int p = tp + tx * 4 + j;
      T[((size_t)(c & 3) * NP + p) * DH + (c >> 2)] = acc[i][j] + bb;
    }
  }
  #undef LOADQKV
  #undef STOREQKV
}

// ---------------------------------------------------------------------------
// Kernel B (fused): one 256-thread block per (b,h,n) row; thread tid owns
// candidate m = tid. scores -> full bitonic sort of 256 sortable u64 keys
// (33 shfl stages in-wave, 3 LDS ping-pong stages cross-wave) -> top-k =
// ranks 0..k-1 -> softmax -> algebraic rotary angles (no atan/sincos) ->
// gather -> reduce. No LDS atomics anywhere.
// ---------------------------------------------------------------------------
__global__ __launch_bounds__(256, 4) void attn_fused_kernel(
    const float* __restrict__ Qt, const float* __restrict__ Kt,
    const float* __restrict__ Vt,
    const float* __restrict__ x_pos, const float* __restrict__ src_pos,
    const float* __restrict__ lrf,
    const int* __restrict__ kptr,
    float* __restrict__ O)
{
  const int tid  = threadIdx.x;
  const int w    = tid >> 6;
  const int lane = tid & 63;
  const int bidx = blockIdx.x;
  const int row  = (bidx & 7) * 512 + (bidx >> 3);  // bijective XCD swizzle
  const int n    = row & (NP - 1);
  const int bh   = row >> 8;
  const int b    = bh >> 2;
  const int h    = bh & 3;

  int kk = *kptr;
  if (kk > 64) kk = 64;
  if (kk < 1) kk = 1;

  __shared__ float qs[DH];
  __shared__ alignas(16) u64 kA[NP];
  __shared__ alignas(16) u64 kB[NP];
  __shared__ float4 ang[64];
  __shared__ float part[4][64];

  if (tid < DH) qs[tid] = Qt[(size_t)row * DH + tid];
  __syncthreads();

  // ---- score for m = tid ---------------------------------------------------
  const float* kbase = Kt + (size_t)bh * NP * DH;
  const float4* q4 = (const float4*)qs;
  const float4* kp = (const float4*)(kbase + (size_t)tid * DH);
  float s = 0.f;
  #pragma unroll
  for (int dd = 0; dd < 16; ++dd) {
    float4 qv = q4[dd], a = kp[dd];
    s += a.x*qv.x + a.y*qv.y + a.z*qv.z + a.w*qv.w;
  }
  s *= 0.125f;

  // sortable key: u32(value) << 32 | (255 - m); descending sort puts
  // larger value first, ties -> smaller m first (matches lax.top_k).
  u32 u = __float_as_uint(s);
  u = (u & 0x80000000u) ? ~u : (u | 0x80000000u);
  u64 v = ((u64)u << 32) | (u32)(255 - tid);

  // ---- bitonic sort, descending across tid = 0..255 ------------------------
  // in-wave passes k = 2..64 (all exchange distances <= 32)
  #pragma unroll
  for (int k = 2; k <= 64; k <<= 1) {
    #pragma unroll
    for (int j = k >> 1; j >= 1; j >>= 1) {
      const bool up = (tid & k) != 0;
      const u64 pv = shfl_xor_u64(v, j);
      const bool takemax = (((tid & j) == 0) != up);
      if ((pv > v) == takemax) v = pv;
    }
  }
  // k = 128: j = 64 cross-wave, then j = 32..1 in-wave
  kA[tid] = v;
  __syncthreads();
  {
    const u64 pv = kA[tid ^ 64];
    const bool up = (tid & 128) != 0;
    const bool takemax = (((tid & 64) == 0) != up);
    if ((pv > v) == takemax) v = pv;
  }
  #pragma unroll
  for (int j = 32; j >= 1; j >>= 1) {
    const bool up = (tid & 128) != 0;
    const u64 pv = shfl_xor_u64(v, j);
    const bool takemax = (((tid & j) == 0) != up);
    if ((pv > v) == takemax) v = pv;
  }
  // k = 256 (descending for all): j = 128, 64 cross-wave, then 32..1 in-wave
  kB[tid] = v;
  __syncthreads();
  {
    const u64 pv = kB[tid ^ 128];
    const bool takemax = ((tid & 128) == 0);
    if ((pv > v) == takemax) v = pv;
  }
  kA[tid] = v;
  __syncthreads();
  {
    const u64 pv = kA[tid ^ 64];
    const bool takemax = ((tid & 64) == 0);
    if ((pv > v) == takemax) v = pv;
  }
  #pragma unroll
  for (int j = 32; j >= 1; j >>= 1) {
    const u64 pv = shfl_xor_u64(v, j);
    const bool takemax = ((tid & j) == 0);
    if ((pv > v) == takemax) v = pv;
  }
  kB[tid] = v;          // kB = keys sorted descending; rank == index
  __syncthreads();

  // ---- softmax over ranks 0..kk-1 (redundant per wave, in-register) --------
  const u32 hm = (u32)(kB[0] >> 32);
  const float vmax = __uint_as_float((hm & 0x80000000u) ? (hm & 0x7fffffffu) : ~hm);
  float e = 0.f;
  if (lane < kk) {
    const u32 hv = (u32)(kB[lane] >> 32);
    const float sv = __uint_as_float((hv & 0x80000000u) ? (hv & 0x7fffffffu) : ~hv);
    e = expf(sv - vmax);
  }
  float ssum = e;
  #pragma unroll
  for (int off = 32; off; off >>= 1) ssum += __shfl_xor(ssum, off);

  // this wave's quarter of the selected set
  const int base = (kk * w) >> 2;
  const int end  = (kk * (w + 1)) >> 2;
  const int cnt4 = end - base;                 // <= 16

  // ---- angles (algebraic; no atan/sincos): one thread per selected elem ----
  const float ej = __shfl(e, (base + lane) & 63);   // e for slot base+lane
  if (lane < cnt4) {
    const int j = base + lane;
    const int msel = 255 - (int)(u32)kB[j];
    const float p = ej / ssum;
    const float* xp = x_pos   + ((size_t)b * NP + msel) * 3;
    const float* sp = src_pos + ((size_t)b * NP + n) * 3;
    const float* L  = lrf     + ((size_t)b * NP + msel) * 9;  // row-major [y][x]
    const float r0 = xp[0] - sp[0], r1 = xp[1] - sp[1], r2v = xp[2] - sp[2];
    const float px = L[0]*r0 + L[3]*r1 + L[6]*r2v;   // lrf^T r
    const float py = L[1]*r0 + L[4]*r1 + L[7]*r2v;
    const float pz = L[2]*r0 + L[5]*r1 + L[8]*r2v;
    // cos/sin(alpha): alpha = atan(py/px) (+pi if px<0), NaN->0
    const float r2 = px*px + py*py;
    const float inv2 = (r2 > 0.f) ? rsqrtf(r2) : 0.f;
    const float ca = (r2 > 0.f) ? px * inv2 : 1.f;
    const float sa = py * inv2;
    // cos/sin(phi): phi = atan(pz / sqrt(px^2+py^2)), NaN->0
    const float r2d = r2 * inv2;                     // sqrt(px^2+py^2)
    const float r3 = r2 + pz * pz;
    const float inv3 = (r3 > 0.f) ? rsqrtf(r3) : 0.f;
    const float cph = (r3 > 0.f) ? r2d * inv3 : 1.f;
    const float sph = pz * inv3;
    ang[j] = make_float4(p * ca, p * sa, p * cph, p * sph);
  }
  __syncthreads();

  // ---- gather + rotate-half + weighted sum (named scalars) -----------------
  const float* vbase = Vt + (size_t)bh * NP * DH;
  const bool useA = ((lane & 3) < 2);          // d%4 in {0,1} -> alpha else phi
  const bool odd  = (lane & 1);
  const int  ev   = lane & ~1;
  float acc = 0.f;

  int j = base;
  for (; j + 4 <= end; j += 4) {
    const int ma = 255 - (int)(u32)kB[j];
    const int mb = 255 - (int)(u32)kB[j+1];
    const int mc = 255 - (int)(u32)kB[j+2];
    const int md = 255 - (int)(u32)kB[j+3];
    const float2 va = *(const float2*)(vbase + (size_t)ma * DH + ev);
    const float2 vb = *(const float2*)(vbase + (size_t)mb * DH + ev);
    const float2 vc = *(const float2*)(vbase + (size_t)mc * DH + ev);
    const float2 vd = *(const float2*)(vbase + (size_t)md * DH + ev);
    const float4 Aa = ang[j], Ab = ang[j+1], Ac = ang[j+2], Ad = ang[j+3];
    float vm, dsc, pc, ps;
    vm = odd ? va.y : va.x;  dsc = odd ? va.x : -va.y;
    pc = useA ? Aa.x : Aa.z; ps  = useA ? Aa.y : Aa.w;
    acc += vm * pc + dsc * ps;
    vm = odd ? vb.y : vb.x;  dsc = odd ? vb.x : -vb.y;
    pc = useA ? Ab.x : Ab.z; ps  = useA ? Ab.y : Ab.w;
    acc += vm * pc + dsc * ps;
    vm = odd ? vc.y : vc.x;  dsc = odd ? vc.x : -vc.y;
    pc = useA ? Ac.x : Ac.z; ps  = useA ? Ac.y : Ac.w;
    acc += vm * pc + dsc * ps;
    vm = odd ? vd.y : vd.x;  dsc = odd ? vd.x : -vd.y;
    pc = useA ? Ad.x : Ad.z; ps  = useA ? Ad.y : Ad.w;
    acc += vm * pc + dsc * ps;
  }
  for (; j < end; ++j) {
    const int m = 255 - (int)(u32)kB[j];
    const float2 v2 = *(const float2*)(vbase + (size_t)m * DH + ev);
    const float4 a  = ang[j];
    const float vm  = odd ? v2.y :  v2.x;
    const float dsc = odd ? v2.x : -v2.y;
    const float pc  = useA ? a.x : a.z;
    const float ps  = useA ? a.y : a.w;
    acc += vm * pc + dsc * ps;
  }

  part[w][lane] = acc;
  __syncthreads();
  if (tid < DH) {
    const float tot = part[0][tid] + part[1][tid] + part[2][tid] + part[3][tid];
    const int c = (tid << 2) | h;              // channel = d*4 + h
    O[((size_t)b * DM + c) * NP + n] = tot;
  }
}

// ---------------------------------------------------------------------------
// Kernel D: final pointwise conv: out[b,co,n] = Wm @ O + bm
// ---------------------------------------------------------------------------
__global__ __launch_bounds__(256) void final_proj_kernel(
    const float* __restrict__ O, const float* __restrict__ Wm,
    const float* __restrict__ bm, float* __restrict__ out)
{
  const int tile = blockIdx.x;
  const int b    = blockIdx.y;
  const int tc = (tile >> 2) * 64;
  const int tp = (tile & 3) * 64;
  const float* X = O + (size_t)b * DM * NP;
  float* Y       = out + (size_t)b * DM * NP;

  __shared__ float Ws[2][32][64];
  __shared__ float Xs[2][32][64];
  const int tid = threadIdx.x;
  const int ty = tid >> 4, tx = tid & 15;
  const int c0 = tid >> 3;
  const int k4 = tid & 7;
  const int pX = tid & 15;
  const int kX = tid >> 4;

  float4 wA, wB, xA, xB;
  #define LOADF(K0)                                                            \
    wA = *(const float4*)&Wm[(size_t)(tc + c0)      * DM + (K0) + k4 * 4];     \
    wB = *(const float4*)&Wm[(size_t)(tc + c0 + 32) * DM + (K0) + k4 * 4];     \
    xA = *(const float4*)&X[(size_t)((K0) + kX)      * NP + tp + pX * 4];      \
    xB = *(const float4*)&X[(size_t)((K0) + kX + 16) * NP + tp + pX * 4];

  #define STOREF(BUF)                                                          \
    Ws[BUF][k4*4+0][c0] = wA.x; Ws[BUF][k4*4+1][c0] = wA.y;                    \
    Ws[BUF][k4*4+2][c0] = wA.z; Ws[BUF][k4*4+3][c0] = wA.w;                    \
    Ws[BUF][k4*4+0][c0+32] = wB.x; Ws[BUF][k4*4+1][c0+32] = wB.y;              \
    Ws[BUF][k4*4+2][c0+32] = wB.z; Ws[BUF][k4*4+3][c0+32] = wB.w;              \
    *(float4*)&Xs[BUF][kX][pX*4]      = xA;                                    \
    *(float4*)&Xs[BUF][kX+16][pX*4]   = xB;

  LOADF(0);
  STOREF(0);
  __syncthreads();

  float acc[4][4];
  #pragma unroll
  for (int i = 0; i < 4; ++i)
    #pragma unroll
    for (int j = 0; j < 4; ++j) acc[i][j] = 0.f;

  for (int ch = 0; ch < 8; ++ch) {
    const int cur = ch & 1;
    if (ch < 7) { LOADF((ch + 1) * 32); }
    #pragma unroll
    for (int kk = 0; kk < 32; ++kk) {
      float4 a = *(const float4*)&Ws[cur][kk][ty * 4];
      float4 xv = *(const float4*)&Xs[cur][kk][tx * 4];
      float av[4] = {a.x, a.y, a.z, a.w};
      float xvv[4] = {xv.x, xv.y, xv.z, xv.w};
      #pragma unroll
      for (int i = 0; i < 4; ++i)
        #pragma unroll
        for (int j = 0; j < 4; ++j) acc[i][j] += av[i] * xvv[j];
    }
    if (ch < 7) {
      STOREF(cur ^ 1);
      __syncthreads();
    }
  }

  #pragma unroll
  for (int i = 0; i < 4; ++i) {
    const int c = tc + ty * 4 + i;
    const float bb = bm[c];
    float4 o4;
    o4.x = acc[i][0] + bb; o4.y = acc[i][1] + bb;
    o4.z = acc[i][2] + bb; o4.w = acc[i][3] + bb;
    *(float4*)&Y[(size_t)c * NP + tp + tx * 4] = o4;
  }
  #undef LOADF
  #undef STOREF
}

// ---------------------------------------------------------------------------
extern "C" void kernel_launch(void* const* d_in, const int* in_sizes, int n_in,
                              void* d_out, int out_size, void* d_ws, size_t ws_size,
                              hipStream_t stream)
{
  const float* x       = (const float*)d_in[0];
  const float* source  = (const float*)d_in[1];
  const float* x_pos   = (const float*)d_in[2];
  const float* src_pos = (const float*)d_in[3];
  const float* lrf     = (const float*)d_in[4];
  const float* Wq = (const float*)d_in[5];
  const float* bq = (const float*)d_in[6];
  const float* Wk = (const float*)d_in[7];
  const float* bk = (const float*)d_in[8];
  const float* Wv = (const float*)d_in[9];
  const float* bv = (const float*)d_in[10];
  const float* Wm = (const float*)d_in[11];
  const float* bm = (const float*)d_in[12];
  const int* kptr = (const int*)d_in[13];
  float* out = (float*)d_out;

  // workspace layout (floats)
  float* ws = (float*)d_ws;
  float* Qt = ws;                         // [4][4][256][64] = 262144
  float* Kt = Qt + 262144;
  float* Vt = Kt + 262144;
  float* O  = Vt + 262144;                // [4][256][256]   = 262144
  // total: 4 MB

  qkv_proj_kernel<<<dim3(16, 3, 4), 256, 0, stream>>>(
      x, source, Wq, bq, Wk, bk, Wv, bv, Qt, Kt, Vt);
  attn_fused_kernel<<<dim3(4096), 256, 0, stream>>>(
      Qt, Kt, Vt, x_pos, src_pos, lrf, kptr, O);
  final_proj_kernel<<<dim3(16, 4), 256, 0, stream>>>(
      O, Wm, bm, out);
}

// Round 7
// 60.005 us; speedup vs baseline: 1.8346x; 1.2313x over previous
//
#include <hip/hip_runtime.h>
#include <math.h>

#define DM 256   // d_model
#define NP 256   // n == m == 256 points
#define NH 4     // heads
#define DH 64    // dim per head

typedef unsigned long long u64;
typedef unsigned int u32;

static __device__ __forceinline__ u64 shfl_xor_u64(u64 x, int m) {
  u32 lo = (u32)x, hi = (u32)(x >> 32);
  lo = __shfl_xor(lo, m);
  hi = __shfl_xor(hi, m);
  return ((u64)hi << 32) | lo;
}

// ---------------------------------------------------------------------------
// Kernel A: Q/K/V pointwise conv (GEMM) + bias -> T[b][h][pt][d].
// ---------------------------------------------------------------------------
__global__ __launch_bounds__(256) void qkv_proj_kernel(
    const float* __restrict__ x, const float* __restrict__ src,
    const float* __restrict__ Wq, const float* __restrict__ bq,
    const float* __restrict__ Wk, const float* __restrict__ bk,
    const float* __restrict__ Wv, const float* __restrict__ bv,
    float* __restrict__ Qt, float* __restrict__ Kt, float* __restrict__ Vt)
{
  const int tile = blockIdx.x;      // 16 tiles: 4x4 grid of 64x64
  const int mat  = blockIdx.y;      // 0=q, 1=k, 2=v
  const int b    = blockIdx.z;
  const int tc = (tile >> 2) * 64;
  const int tp = (tile & 3) * 64;
  const float* W    = (mat == 0) ? Wq : (mat == 1) ? Wk : Wv;
  const float* bias = (mat == 0) ? bq : (mat == 1) ? bk : bv;
  const float* X    = ((mat == 0) ? x : src) + (size_t)b * DM * NP;
  float* T          = ((mat == 0) ? Qt : (mat == 1) ? Kt : Vt) + (size_t)b * NH * NP * DH;

  __shared__ float Ws[2][32][64];
  __shared__ float Xs[2][32][64];
  const int tid = threadIdx.x;
  const int ty = tid >> 4, tx = tid & 15;
  const int c0 = tid >> 3;
  const int k4 = tid & 7;
  const int pX = tid & 15;
  const int kX = tid >> 4;

  float4 wA, wB, xA, xB;
  #define LOADQKV(K0)                                                          \
    wA = *(const float4*)&W[(size_t)(tc + c0)      * DM + (K0) + k4 * 4];      \
    wB = *(const float4*)&W[(size_t)(tc + c0 + 32) * DM + (K0) + k4 * 4];      \
    xA = *(const float4*)&X[(size_t)((K0) + kX)      * NP + tp + pX * 4];      \
    xB = *(const float4*)&X[(size_t)((K0) + kX + 16) * NP + tp + pX * 4];

  #define STOREQKV(BUF)                                                        \
    Ws[BUF][k4*4+0][c0] = wA.x; Ws[BUF][k4*4+1][c0] = wA.y;                    \
    Ws[BUF][k4*4+2][c0] = wA.z; Ws[BUF][k4*4+3][c0] = wA.w;                    \
    Ws[BUF][k4*4+0][c0+32] = wB.x; Ws[BUF][k4*4+1][c0+32] = wB.y;              \
    Ws[BUF][k4*4+2][c0+32] = wB.z; Ws[BUF][k4*4+3][c0+32] = wB.w;              \
    *(float4*)&Xs[BUF][kX][pX*4]      = xA;                                    \
    *(float4*)&Xs[BUF][kX+16][pX*4]   = xB;

  LOADQKV(0);
  STOREQKV(0);
  __syncthreads();

  float acc[4][4];
  #pragma unroll
  for (int i = 0; i < 4; ++i)
    #pragma unroll
    for (int j = 0; j < 4; ++j) acc[i][j] = 0.f;

  for (int ch = 0; ch < 8; ++ch) {
    const int cur = ch & 1;
    if (ch < 7) { LOADQKV((ch + 1) * 32); }
    #pragma unroll
    for (int kk = 0; kk < 32; ++kk) {
      float4 a = *(const float4*)&Ws[cur][kk][ty * 4];
      float4 xv = *(const float4*)&Xs[cur][kk][tx * 4];
      float av[4] = {a.x, a.y, a.z, a.w};
      float xvv[4] = {xv.x, xv.y, xv.z, xv.w};
      #pragma unroll
      for (int i = 0; i < 4; ++i)
        #pragma unroll
        for (int j = 0; j < 4; ++j) acc[i][j] += av[i] * xvv[j];
    }
    if (ch < 7) {
      STOREQKV(cur ^ 1);
      __syncthreads();
    }
  }

  #pragma unroll
  for (int i = 0; i < 4; ++i) {
    const int c = tc + ty * 4 + i;
    const float bb = bias[c];
    #pragma unroll
    for (int j = 0; j < 4; ++j) {
      const int p = tp + tx * 4 + j;
      T[((size_t)(c & 3) * NP + p) * DH + (c >> 2)] = acc[i][j] + bb;
    }
  }
  #undef LOADQKV
  #undef STOREQKV
}

// ---------------------------------------------------------------------------
// Kernel B: batched score GEMM: scores[bh][n][m] = (Q[n,:] . K[m,:]) / 8.
// 64x64 output tile per block, K = 64 staged once in LDS transposed [d][n|m]
// (+4 pad keeps b128 rows 16B-aligned and reads ~conflict-free).
// ---------------------------------------------------------------------------
__global__ __launch_bounds__(256) void score_gemm_kernel(
    const float* __restrict__ Qt, const float* __restrict__ Kt,
    float* __restrict__ scores)
{
  const int tile = blockIdx.x;          // 16 = 4x4 tiles of 64x64
  const int bh   = blockIdx.y;          // 16
  const int tn = (tile >> 2) * 64;
  const int tm = (tile & 3) * 64;
  const float* Qb = Qt + (size_t)bh * NP * DH;
  const float* Kb = Kt + (size_t)bh * NP * DH;

  __shared__ float Qs[64][68];   // [d][n]
  __shared__ float Ks[64][68];   // [d][m]
  const int tid = threadIdx.x;

  #pragma unroll
  for (int p = 0; p < 4; ++p) {
    const int u = tid + p * 256;       // 1024 float4 per matrix
    const int r = u >> 4;              // point row 0..63
    const int g = u & 15;              // d-group
    const float4 qv = *(const float4*)&Qb[(size_t)(tn + r) * DH + g * 4];
    const float4 kv = *(const float4*)&Kb[(size_t)(tm + r) * DH + g * 4];
    Qs[g*4+0][r] = qv.x; Qs[g*4+1][r] = qv.y;
    Qs[g*4+2][r] = qv.z; Qs[g*4+3][r] = qv.w;
    Ks[g*4+0][r] = kv.x; Ks[g*4+1][r] = kv.y;
    Ks[g*4+2][r] = kv.z; Ks[g*4+3][r] = kv.w;
  }
  __syncthreads();

  const int ty = tid >> 4, tx = tid & 15;
  float acc[4][4];
  #pragma unroll
  for (int i = 0; i < 4; ++i)
    #pragma unroll
    for (int j = 0; j < 4; ++j) acc[i][j] = 0.f;

  #pragma unroll 4
  for (int d = 0; d < DH; ++d) {
    const float4 a = *(const float4*)&Qs[d][ty * 4];
    const float4 bv = *(const float4*)&Ks[d][tx * 4];
    const float av[4] = {a.x, a.y, a.z, a.w};
    const float bvv[4] = {bv.x, bv.y, bv.z, bv.w};
    #pragma unroll
    for (int i = 0; i < 4; ++i)
      #pragma unroll
      for (int j = 0; j < 4; ++j) acc[i][j] += av[i] * bvv[j];
  }

  float* srow = scores + ((size_t)bh * NP + tn) * NP + tm;
  #pragma unroll
  for (int i = 0; i < 4; ++i) {
    float4 o4;
    o4.x = acc[i][0] * 0.125f; o4.y = acc[i][1] * 0.125f;
    o4.z = acc[i][2] * 0.125f; o4.w = acc[i][3] * 0.125f;
    *(float4*)&srow[(size_t)(ty * 4 + i) * NP + tx * 4] = o4;
  }
}

// ---------------------------------------------------------------------------
// Kernel C (fused top-k): one 256-thread block per (b,h,n) row; thread tid
// owns score m = tid (coalesced 1KB row read). Bitonic sort of sortable u64
// keys -> top-k = ranks 0..k-1 -> softmax -> algebraic rotary angles ->
// uniform-m gather -> reduce.
// ---------------------------------------------------------------------------
__global__ __launch_bounds__(256) void attn_topk_kernel(
    const float* __restrict__ scores, const float* __restrict__ Vt,
    const float* __restrict__ x_pos, const float* __restrict__ src_pos,
    const float* __restrict__ lrf,
    const int* __restrict__ kptr,
    float* __restrict__ O)
{
  const int tid  = threadIdx.x;
  const int w    = tid >> 6;
  const int lane = tid & 63;
  const int bidx = blockIdx.x;
  const int row  = (bidx & 7) * 512 + (bidx >> 3);  // bijective XCD swizzle
  const int n    = row & (NP - 1);
  const int bh   = row >> 8;
  const int b    = bh >> 2;
  const int h    = bh & 3;

  int kk = *kptr;
  if (kk > 64) kk = 64;
  if (kk < 1) kk = 1;

  __shared__ alignas(16) u64 kA[NP];
  __shared__ alignas(16) u64 kB[NP];
  __shared__ float4 ang[64];
  __shared__ float part[4][64];

  // ---- coalesced score read ------------------------------------------------
  const float s = scores[(size_t)row * NP + tid];

  // sortable key: u32(value) << 32 | (255 - m); descending sort puts
  // larger value first, ties -> smaller m first (matches lax.top_k).
  u32 u = __float_as_uint(s);
  u = (u & 0x80000000u) ? ~u : (u | 0x80000000u);
  u64 v = ((u64)u << 32) | (u32)(255 - tid);

  // ---- bitonic sort, descending across tid = 0..255 ------------------------
  #pragma unroll
  for (int k = 2; k <= 64; k <<= 1) {
    #pragma unroll
    for (int j = k >> 1; j >= 1; j >>= 1) {
      const bool up = (tid & k) != 0;
      const u64 pv = shfl_xor_u64(v, j);
      const bool takemax = (((tid & j) == 0) != up);
      if ((pv > v) == takemax) v = pv;
    }
  }
  kA[tid] = v;
  __syncthreads();
  {
    const u64 pv = kA[tid ^ 64];
    const bool up = (tid & 128) != 0;
    const bool takemax = (((tid & 64) == 0) != up);
    if ((pv > v) == takemax) v = pv;
  }
  #pragma unroll
  for (int j = 32; j >= 1; j >>= 1) {
    const bool up = (tid & 128) != 0;
    const u64 pv = shfl_xor_u64(v, j);
    const bool takemax = (((tid & j) == 0) != up);
    if ((pv > v) == takemax) v = pv;
  }
  kB[tid] = v;
  __syncthreads();
  {
    const u64 pv = kB[tid ^ 128];
    const bool takemax = ((tid & 128) == 0);
    if ((pv > v) == takemax) v = pv;
  }
  kA[tid] = v;
  __syncthreads();
  {
    const u64 pv = kA[tid ^ 64];
    const bool takemax = ((tid & 64) == 0);
    if ((pv > v) == takemax) v = pv;
  }
  #pragma unroll
  for (int j = 32; j >= 1; j >>= 1) {
    const u64 pv = shfl_xor_u64(v, j);
    const bool takemax = ((tid & j) == 0);
    if ((pv > v) == takemax) v = pv;
  }
  kB[tid] = v;          // kB = keys sorted descending; rank == index
  __syncthreads();

  // ---- softmax over ranks 0..kk-1 (redundant per wave, in-register) --------
  const u32 hm = (u32)(kB[0] >> 32);
  const float vmax = __uint_as_float((hm & 0x80000000u) ? (hm & 0x7fffffffu) : ~hm);
  float e = 0.f;
  if (lane < kk) {
    const u32 hv = (u32)(kB[lane] >> 32);
    const float sv = __uint_as_float((hv & 0x80000000u) ? (hv & 0x7fffffffu) : ~hv);
    e = expf(sv - vmax);
  }
  float ssum = e;
  #pragma unroll
  for (int off = 32; off; off >>= 1) ssum += __shfl_xor(ssum, off);

  // this wave's quarter of the selected set
  const int base = (kk * w) >> 2;
  const int end  = (kk * (w + 1)) >> 2;
  const int cnt4 = end - base;                 // <= 16

  // ---- angles (algebraic; no atan/sincos): one thread per selected elem ----
  const float ej = __shfl(e, (base + lane) & 63);   // e for slot base+lane
  if (lane < cnt4) {
    const int j = base + lane;
    const int msel = 255 - (int)(u32)kB[j];
    const float p = ej / ssum;
    const float* xp = x_pos   + ((size_t)b * NP + msel) * 3;
    const float* sp = src_pos + ((size_t)b * NP + n) * 3;
    const float* L  = lrf     + ((size_t)b * NP + msel) * 9;  // row-major [y][x]
    const float r0 = xp[0] - sp[0], r1 = xp[1] - sp[1], r2v = xp[2] - sp[2];
    const float px = L[0]*r0 + L[3]*r1 + L[6]*r2v;   // lrf^T r
    const float py = L[1]*r0 + L[4]*r1 + L[7]*r2v;
    const float pz = L[2]*r0 + L[5]*r1 + L[8]*r2v;
    const float r2 = px*px + py*py;
    const float inv2 = (r2 > 0.f) ? rsqrtf(r2) : 0.f;
    const float ca = (r2 > 0.f) ? px * inv2 : 1.f;
    const float sa = py * inv2;
    const float r2d = r2 * inv2;                     // sqrt(px^2+py^2)
    const float r3 = r2 + pz * pz;
    const float inv3 = (r3 > 0.f) ? rsqrtf(r3) : 0.f;
    const float cph = (r3 > 0.f) ? r2d * inv3 : 1.f;
    const float sph = pz * inv3;
    ang[j] = make_float4(p * ca, p * sa, p * cph, p * sph);
  }
  __syncthreads();

  // ---- gather + rotate-half + weighted sum (uniform m -> coalesced) --------
  const float* vbase = Vt + (size_t)bh * NP * DH;
  const bool useA = ((lane & 3) < 2);          // d%4 in {0,1} -> alpha else phi
  const bool odd  = (lane & 1);
  const int  ev   = lane & ~1;
  float acc = 0.f;

  int j = base;
  for (; j + 4 <= end; j += 4) {
    const int ma = 255 - (int)(u32)kB[j];
    const int mb = 255 - (int)(u32)kB[j+1];
    const int mc = 255 - (int)(u32)kB[j+2];
    const int md = 255 - (int)(u32)kB[j+3];
    const float2 va = *(const float2*)(vbase + (size_t)ma * DH + ev);
    const float2 vb = *(const float2*)(vbase + (size_t)mb * DH + ev);
    const float2 vc = *(const float2*)(vbase + (size_t)mc * DH + ev);
    const float2 vd = *(const float2*)(vbase + (size_t)md * DH + ev);
    const float4 Aa = ang[j], Ab = ang[j+1], Ac = ang[j+2], Ad = ang[j+3];
    float vm, dsc, pc, ps;
    vm = odd ? va.y : va.x;  dsc = odd ? va.x : -va.y;
    pc = useA ? Aa.x : Aa.z; ps  = useA ? Aa.y : Aa.w;
    acc += vm * pc + dsc * ps;
    vm = odd ? vb.y : vb.x;  dsc = odd ? vb.x : -vb.y;
    pc = useA ? Ab.x : Ab.z; ps  = useA ? Ab.y : Ab.w;
    acc += vm * pc + dsc * ps;
    vm = odd ? vc.y : vc.x;  dsc = odd ? vc.x : -vc.y;
    pc = useA ? Ac.x : Ac.z; ps  = useA ? Ac.y : Ac.w;
    acc += vm * pc + dsc * ps;
    vm = odd ? vd.y : vd.x;  dsc = odd ? vd.x : -vd.y;
    pc = useA ? Ad.x : Ad.z; ps  = useA ? Ad.y : Ad.w;
    acc += vm * pc + dsc * ps;
  }
  for (; j < end; ++j) {
    const int m = 255 - (int)(u32)kB[j];
    const float2 v2 = *(const float2*)(vbase + (size_t)m * DH + ev);
    const float4 a  = ang[j];
    const float vm  = odd ? v2.y :  v2.x;
    const float dsc = odd ? v2.x : -v2.y;
    const float pc  = useA ? a.x : a.z;
    const float ps  = useA ? a.y : a.w;
    acc += vm * pc + dsc * ps;
  }

  part[w][lane] = acc;
  __syncthreads();
  if (tid < DH) {
    const float tot = part[0][tid] + part[1][tid] + part[2][tid] + part[3][tid];
    const int c = (tid << 2) | h;              // channel = d*4 + h
    O[((size_t)b * DM + c) * NP + n] = tot;
  }
}

// ---------------------------------------------------------------------------
// Kernel D: final pointwise conv: out[b,co,n] = Wm @ O + bm
// ---------------------------------------------------------------------------
__global__ __launch_bounds__(256) void final_proj_kernel(
    const float* __restrict__ O, const float* __restrict__ Wm,
    const float* __restrict__ bm, float* __restrict__ out)
{
  const int tile = blockIdx.x;
  const int b    = blockIdx.y;
  const int tc = (tile >> 2) * 64;
  const int tp = (tile & 3) * 64;
  const float* X = O + (size_t)b * DM * NP;
  float* Y       = out + (size_t)b * DM * NP;

  __shared__ float Ws[2][32][64];
  __shared__ float Xs[2][32][64];
  const int tid = threadIdx.x;
  const int ty = tid >> 4, tx = tid & 15;
  const int c0 = tid >> 3;
  const int k4 = tid & 7;
  const int pX = tid & 15;
  const int kX = tid >> 4;

  float4 wA, wB, xA, xB;
  #define LOADF(K0)                                                            \
    wA = *(const float4*)&Wm[(size_t)(tc + c0)      * DM + (K0) + k4 * 4];     \
    wB = *(const float4*)&Wm[(size_t)(tc + c0 + 32) * DM + (K0) + k4 * 4];     \
    xA = *(const float4*)&X[(size_t)((K0) + kX)      * NP + tp + pX * 4];      \
    xB = *(const float4*)&X[(size_t)((K0) + kX + 16) * NP + tp + pX * 4];

  #define STOREF(BUF)                                                          \
    Ws[BUF][k4*4+0][c0] = wA.x; Ws[BUF][k4*4+1][c0] = wA.y;                    \
    Ws[BUF][k4*4+2][c0] = wA.z; Ws[BUF][k4*4+3][c0] = wA.w;                    \
    Ws[BUF][k4*4+0][c0+32] = wB.x; Ws[BUF][k4*4+1][c0+32] = wB.y;              \
    Ws[BUF][k4*4+2][c0+32] = wB.z; Ws[BUF][k4*4+3][c0+32] = wB.w;              \
    *(float4*)&Xs[BUF][kX][pX*4]      = xA;                                    \
    *(float4*)&Xs[BUF][kX+16][pX*4]   = xB;

  LOADF(0);
  STOREF(0);
  __syncthreads();

  float acc[4][4];
  #pragma unroll
  for (int i = 0; i < 4; ++i)
    #pragma unroll
    for (int j = 0; j < 4; ++j) acc[i][j] = 0.f;

  for (int ch = 0; ch < 8; ++ch) {
    const int cur = ch & 1;
    if (ch < 7) { LOADF((ch + 1) * 32); }
    #pragma unroll
    for (int kk = 0; kk < 32; ++kk) {
      float4 a = *(const float4*)&Ws[cur][kk][ty * 4];
      float4 xv = *(const float4*)&Xs[cur][kk][tx * 4];
      float av[4] = {a.x, a.y, a.z, a.w};
      float xvv[4] = {xv.x, xv.y, xv.z, xv.w};
      #pragma unroll
      for (int i = 0; i < 4; ++i)
        #pragma unroll
        for (int j = 0; j < 4; ++j) acc[i][j] += av[i] * xvv[j];
    }
    if (ch < 7) {
      STOREF(cur ^ 1);
      __syncthreads();
    }
  }

  #pragma unroll
  for (int i = 0; i < 4; ++i) {
    const int c = tc + ty * 4 + i;
    const float bb = bm[c];
    float4 o4;
    o4.x = acc[i][0] + bb; o4.y = acc[i][1] + bb;
    o4.z = acc[i][2] + bb; o4.w = acc[i][3] + bb;
    *(float4*)&Y[(size_t)c * NP + tp + tx * 4] = o4;
  }
  #undef LOADF
  #undef STOREF
}

// ---------------------------------------------------------------------------
extern "C" void kernel_launch(void* const* d_in, const int* in_sizes, int n_in,
                              void* d_out, int out_size, void* d_ws, size_t ws_size,
                              hipStream_t stream)
{
  const float* x       = (const float*)d_in[0];
  const float* source  = (const float*)d_in[1];
  const float* x_pos   = (const float*)d_in[2];
  const float* src_pos = (const float*)d_in[3];
  const float* lrf     = (const float*)d_in[4];
  const float* Wq = (const float*)d_in[5];
  const float* bq = (const float*)d_in[6];
  const float* Wk = (const float*)d_in[7];
  const float* bk = (const float*)d_in[8];
  const float* Wv = (const float*)d_in[9];
  const float* bv = (const float*)d_in[10];
  const float* Wm = (const float*)d_in[11];
  const float* bm = (const float*)d_in[12];
  const int* kptr = (const int*)d_in[13];
  float* out = (float*)d_out;

  // workspace layout (floats)
  float* ws = (float*)d_ws;
  float* Qt = ws;                         // [16][256][64]  = 262144
  float* Kt = Qt + 262144;
  float* Vt = Kt + 262144;
  float* O  = Vt + 262144;                // [4][256][256]  = 262144
  float* scores = O + 262144;             // [16][256][256] = 1048576
  // total: 8 MB

  qkv_proj_kernel<<<dim3(16, 3, 4), 256, 0, stream>>>(
      x, source, Wq, bq, Wk, bk, Wv, bv, Qt, Kt, Vt);
  score_gemm_kernel<<<dim3(16, 16), 256, 0, stream>>>(
      Qt, Kt, scores);
  attn_topk_kernel<<<dim3(4096), 256, 0, stream>>>(
      scores, Vt, x_pos, src_pos, lrf, kptr, O);
  final_proj_kernel<<<dim3(16, 4), 256, 0, stream>>>(
      O, Wm, bm, out);
}

// Round 9
// 52.462 us; speedup vs baseline: 2.0983x; 1.1438x over previous
//
#include <hip/hip_runtime.h>
#include <math.h>

#define DM 256   // d_model
#define NP 256   // n == m == 256 points
#define NH 4     // heads
#define DH 64    // dim per head

typedef unsigned long long u64;
typedef unsigned int u32;

// ---------------------------------------------------------------------------
// Kernel A: Q/K/V pointwise conv (GEMM) + bias -> T[b][h][pt][d]. (R7-proven)
// ---------------------------------------------------------------------------
__global__ __launch_bounds__(256) void qkv_proj_kernel(
    const float* __restrict__ x, const float* __restrict__ src,
    const float* __restrict__ Wq, const float* __restrict__ bq,
    const float* __restrict__ Wk, const float* __restrict__ bk,
    const float* __restrict__ Wv, const float* __restrict__ bv,
    float* __restrict__ Qt, float* __restrict__ Kt, float* __restrict__ Vt)
{
  const int tile = blockIdx.x;      // 16 tiles: 4x4 grid of 64x64
  const int mat  = blockIdx.y;      // 0=q, 1=k, 2=v
  const int b    = blockIdx.z;
  const int tc = (tile >> 2) * 64;
  const int tp = (tile & 3) * 64;
  const float* W    = (mat == 0) ? Wq : (mat == 1) ? Wk : Wv;
  const float* bias = (mat == 0) ? bq : (mat == 1) ? bk : bv;
  const float* X    = ((mat == 0) ? x : src) + (size_t)b * DM * NP;
  float* T          = ((mat == 0) ? Qt : (mat == 1) ? Kt : Vt) + (size_t)b * NH * NP * DH;

  __shared__ float Ws[2][32][64];
  __shared__ float Xs[2][32][64];
  const int tid = threadIdx.x;
  const int ty = tid >> 4, tx = tid & 15;
  const int c0 = tid >> 3;
  const int k4 = tid & 7;
  const int pX = tid & 15;
  const int kX = tid >> 4;

  float4 wA, wB, xA, xB;
  #define LOADQKV(K0)                                                          \
    wA = *(const float4*)&W[(size_t)(tc + c0)      * DM + (K0) + k4 * 4];      \
    wB = *(const float4*)&W[(size_t)(tc + c0 + 32) * DM + (K0) + k4 * 4];      \
    xA = *(const float4*)&X[(size_t)((K0) + kX)      * NP + tp + pX * 4];      \
    xB = *(const float4*)&X[(size_t)((K0) + kX + 16) * NP + tp + pX * 4];

  #define STOREQKV(BUF)                                                        \
    Ws[BUF][k4*4+0][c0] = wA.x; Ws[BUF][k4*4+1][c0] = wA.y;                    \
    Ws[BUF][k4*4+2][c0] = wA.z; Ws[BUF][k4*4+3][c0] = wA.w;                    \
    Ws[BUF][k4*4+0][c0+32] = wB.x; Ws[BUF][k4*4+1][c0+32] = wB.y;              \
    Ws[BUF][k4*4+2][c0+32] = wB.z; Ws[BUF][k4*4+3][c0+32] = wB.w;              \
    *(float4*)&Xs[BUF][kX][pX*4]      = xA;                                    \
    *(float4*)&Xs[BUF][kX+16][pX*4]   = xB;

  LOADQKV(0);
  STOREQKV(0);
  __syncthreads();

  float acc[4][4];
  #pragma unroll
  for (int i = 0; i < 4; ++i)
    #pragma unroll
    for (int j = 0; j < 4; ++j) acc[i][j] = 0.f;

  for (int ch = 0; ch < 8; ++ch) {
    const int cur = ch & 1;
    if (ch < 7) { LOADQKV((ch + 1) * 32); }
    #pragma unroll
    for (int kk = 0; kk < 32; ++kk) {
      float4 a = *(const float4*)&Ws[cur][kk][ty * 4];
      float4 xv = *(const float4*)&Xs[cur][kk][tx * 4];
      float av[4] = {a.x, a.y, a.z, a.w};
      float xvv[4] = {xv.x, xv.y, xv.z, xv.w};
      #pragma unroll
      for (int i = 0; i < 4; ++i)
        #pragma unroll
        for (int j = 0; j < 4; ++j) acc[i][j] += av[i] * xvv[j];
    }
    if (ch < 7) {
      STOREQKV(cur ^ 1);
      __syncthreads();
    }
  }

  #pragma unroll
  for (int i = 0; i < 4; ++i) {
    const int c = tc + ty * 4 + i;
    const float bb = bias[c];
    #pragma unroll
    for (int j = 0; j < 4; ++j) {
      const int p = tp + tx * 4 + j;
      T[((size_t)(c & 3) * NP + p) * DH + (c >> 2)] = acc[i][j] + bb;
    }
  }
  #undef LOADQKV
  #undef STOREQKV
}

// ---------------------------------------------------------------------------
// Kernel B: batched score GEMM (R7-proven): scores[bh][n][m] = Q.K / 8.
// ---------------------------------------------------------------------------
__global__ __launch_bounds__(256) void score_gemm_kernel(
    const float* __restrict__ Qt, const float* __restrict__ Kt,
    float* __restrict__ scores)
{
  const int tile = blockIdx.x;          // 16 = 4x4 tiles of 64x64
  const int bh   = blockIdx.y;          // 16
  const int tn = (tile >> 2) * 64;
  const int tm = (tile & 3) * 64;
  const float* Qb = Qt + (size_t)bh * NP * DH;
  const float* Kb = Kt + (size_t)bh * NP * DH;

  __shared__ float Qs[64][68];   // [d][n]
  __shared__ float Ks[64][68];   // [d][m]
  const int tid = threadIdx.x;

  #pragma unroll
  for (int p = 0; p < 4; ++p) {
    const int u = tid + p * 256;
    const int r = u >> 4;
    const int g = u & 15;
    const float4 qv = *(const float4*)&Qb[(size_t)(tn + r) * DH + g * 4];
    const float4 kv = *(const float4*)&Kb[(size_t)(tm + r) * DH + g * 4];
    Qs[g*4+0][r] = qv.x; Qs[g*4+1][r] = qv.y;
    Qs[g*4+2][r] = qv.z; Qs[g*4+3][r] = qv.w;
    Ks[g*4+0][r] = kv.x; Ks[g*4+1][r] = kv.y;
    Ks[g*4+2][r] = kv.z; Ks[g*4+3][r] = kv.w;
  }
  __syncthreads();

  const int ty = tid >> 4, tx = tid & 15;
  float acc[4][4];
  #pragma unroll
  for (int i = 0; i < 4; ++i)
    #pragma unroll
    for (int j = 0; j < 4; ++j) acc[i][j] = 0.f;

  #pragma unroll 4
  for (int d = 0; d < DH; ++d) {
    const float4 a = *(const float4*)&Qs[d][ty * 4];
    const float4 bv = *(const float4*)&Ks[d][tx * 4];
    const float av[4] = {a.x, a.y, a.z, a.w};
    const float bvv[4] = {bv.x, bv.y, bv.z, bv.w};
    #pragma unroll
    for (int i = 0; i < 4; ++i)
      #pragma unroll
      for (int j = 0; j < 4; ++j) acc[i][j] += av[i] * bvv[j];
  }

  float* srow = scores + ((size_t)bh * NP + tn) * NP + tm;
  #pragma unroll
  for (int i = 0; i < 4; ++i) {
    float4 o4;
    o4.x = acc[i][0] * 0.125f; o4.y = acc[i][1] * 0.125f;
    o4.z = acc[i][2] * 0.125f; o4.w = acc[i][3] * 0.125f;
    *(float4*)&srow[(size_t)(ty * 4 + i) * NP + tx * 4] = o4;
  }
}

// ---------------------------------------------------------------------------
// Kernel C: ballot-radix top-k, one wave per row (4 rows per 256-block).
// Lane holds 4 scores (m = lane*4+r). Keys (value, 255-m) are distinct.
// Phase 1: 32-iter ballot binary search -> T = value of kth-largest key.
// Phase 2: 8-iter ballot search over ties -> Lo; sel = u>T || (u==T && low>=Lo)
// selects EXACTLY k (same set as the R7 sort). Compaction via lanemask
// popcount; coef/m broadcast via LDS (proven pattern, no readlane).
// ---------------------------------------------------------------------------
__global__ __launch_bounds__(256) void attn_topk_kernel(
    const float* __restrict__ scores, const float* __restrict__ Vt,
    const float* __restrict__ x_pos, const float* __restrict__ src_pos,
    const float* __restrict__ lrf,
    const int* __restrict__ kptr,
    float* __restrict__ O)
{
  const int tid  = threadIdx.x;
  const int wid  = tid >> 6;
  const int lane = tid & 63;
  const int bidx = blockIdx.x;                      // 0..1023
  const int rb   = (bidx & 7) * 128 + (bidx >> 3);  // bijective XCD swizzle
  const int row  = rb * 4 + wid;                    // bh*256 + n (4 rows share bh)
  const int n    = row & (NP - 1);
  const int bh   = row >> 8;
  const int b    = bh >> 2;
  const int h    = bh & 3;

  int kk = *kptr;
  if (kk > 64) kk = 64;
  if (kk < 1) kk = 1;

  __shared__ float  eslot[4][64];
  __shared__ int    msel[4][64];
  __shared__ float4 ang[4][64];
  __shared__ float  otile[4][64];

  // ---- 4 scores per lane (coalesced 1KB row read) --------------------------
  const float4 s4 = *(const float4*)&scores[(size_t)row * NP + lane * 4];
  float s[4] = { s4.x, s4.y, s4.z, s4.w };
  u32 u[4], lowv[4];
  #pragma unroll
  for (int r = 0; r < 4; ++r) {
    u32 bb = __float_as_uint(s[r]);
    u[r] = (bb & 0x80000000u) ? ~bb : (bb | 0x80000000u);
    lowv[r] = (u32)(255 - (lane * 4 + r));
  }

  // ---- phase 1: T = value-bits of kth largest ------------------------------
  u32 T = 0u;
  #pragma unroll
  for (int bit = 31; bit >= 0; --bit) {
    const u32 cand = T | (1u << bit);
    int c = 0;
    #pragma unroll
    for (int r = 0; r < 4; ++r) c += __popcll(__ballot(u[r] >= cand));
    if (c >= kk) T = cand;
  }
  int c_gt = 0;
  #pragma unroll
  for (int r = 0; r < 4; ++r) c_gt += __popcll(__ballot(u[r] > T));

  // ---- phase 2: tie-break threshold on low bits (255-m) --------------------
  u32 Lo = 0u;
  #pragma unroll
  for (int bit = 7; bit >= 0; --bit) {
    const u32 cand = Lo | (1u << bit);
    int c = c_gt;
    #pragma unroll
    for (int r = 0; r < 4; ++r)
      c += __popcll(__ballot((u[r] == T) && (lowv[r] >= cand)));
    if (c >= kk) Lo = cand;
  }

  // ---- membership (exactly kk), e-values, Z ---------------------------------
  const float sT = __uint_as_float((T & 0x80000000u) ? (T & 0x7fffffffu) : ~T);
  bool sel[4]; float e[4]; u64 selm[4];
  #pragma unroll
  for (int r = 0; r < 4; ++r) {
    sel[r] = (u[r] > T) || ((u[r] == T) && (lowv[r] >= Lo));
    e[r] = sel[r] ? expf(s[r] - sT) : 0.f;
    selm[r] = __ballot(sel[r]);
  }
  float z = e[0] + e[1] + e[2] + e[3];
  #pragma unroll
  for (int off = 32; off; off >>= 1) z += __shfl_xor(z, off);

  // ---- compaction: slot by (r-major, lane) order ----------------------------
  const u64 lt = (1ull << lane) - 1ull;
  int base = 0;
  #pragma unroll
  for (int r = 0; r < 4; ++r) {
    if (sel[r]) {
      const int slot = base + __popcll(selm[r] & lt);
      eslot[wid][slot] = e[r];
      msel[wid][slot]  = lane * 4 + r;
    }
    base += __popcll(selm[r]);
  }

  // ---- lane j computes rotary-angle coefficients for slot j (in-wave LDS) --
  if (lane < kk) {
    const float ej = eslot[wid][lane];
    const int   mj = msel[wid][lane];
    const float p = ej / z;
    const float* xp = x_pos   + ((size_t)b * NP + mj) * 3;
    const float* sp = src_pos + ((size_t)b * NP + n) * 3;
    const float* L  = lrf     + ((size_t)b * NP + mj) * 9;  // row-major [y][x]
    const float r0 = xp[0] - sp[0], r1 = xp[1] - sp[1], r2v = xp[2] - sp[2];
    const float px = L[0]*r0 + L[3]*r1 + L[6]*r2v;   // lrf^T r
    const float py = L[1]*r0 + L[4]*r1 + L[7]*r2v;
    const float pz = L[2]*r0 + L[5]*r1 + L[8]*r2v;
    const float r2 = px*px + py*py;
    const float inv2 = (r2 > 0.f) ? rsqrtf(r2) : 0.f;
    const float ca = (r2 > 0.f) ? px * inv2 : 1.f;
    const float sa = py * inv2;
    const float r2d = r2 * inv2;                     // sqrt(px^2+py^2)
    const float r3 = r2 + pz * pz;
    const float inv3 = (r3 > 0.f) ? rsqrtf(r3) : 0.f;
    const float cph = (r3 > 0.f) ? r2d * inv3 : 1.f;
    const float sph = pz * inv3;
    ang[wid][lane] = make_float4(p * ca, p * sa, p * cph, p * sph);
  }

  // ---- gather: LDS broadcast coefs + coalesced V float2 loads ---------------
  const float* vbase = Vt + (size_t)bh * NP * DH;
  const bool useA = ((lane & 3) < 2);   // d%4 in {0,1} -> alpha else phi
  const bool odd  = (lane & 1);
  const int  ev   = lane & ~1;
  float acc = 0.f;

  int j = 0;
  for (; j + 4 <= kk; j += 4) {
    const int ma = msel[wid][j],   mb = msel[wid][j+1];
    const int mc = msel[wid][j+2], md = msel[wid][j+3];
    const float4 Aa = ang[wid][j],   Ab = ang[wid][j+1];
    const float4 Ac = ang[wid][j+2], Ad = ang[wid][j+3];
    const float2 va = *(const float2*)(vbase + (size_t)ma * DH + ev);
    const float2 vb = *(const float2*)(vbase + (size_t)mb * DH + ev);
    const float2 vc = *(const float2*)(vbase + (size_t)mc * DH + ev);
    const float2 vd = *(const float2*)(vbase + (size_t)md * DH + ev);
    float vm, dsc, pc, ps;
    vm = odd ? va.y : va.x;  dsc = odd ? va.x : -va.y;
    pc = useA ? Aa.x : Aa.z; ps  = useA ? Aa.y : Aa.w;
    acc += vm * pc + dsc * ps;
    vm = odd ? vb.y : vb.x;  dsc = odd ? vb.x : -vb.y;
    pc = useA ? Ab.x : Ab.z; ps  = useA ? Ab.y : Ab.w;
    acc += vm * pc + dsc * ps;
    vm = odd ? vc.y : vc.x;  dsc = odd ? vc.x : -vc.y;
    pc = useA ? Ac.x : Ac.z; ps  = useA ? Ac.y : Ac.w;
    acc += vm * pc + dsc * ps;
    vm = odd ? vd.y : vd.x;  dsc = odd ? vd.x : -vd.y;
    pc = useA ? Ad.x : Ad.z; ps  = useA ? Ad.y : Ad.w;
    acc += vm * pc + dsc * ps;
  }
  for (; j < kk; ++j) {
    const int m = msel[wid][j];
    const float4 A = ang[wid][j];
    const float2 v2 = *(const float2*)(vbase + (size_t)m * DH + ev);
    const float vm  = odd ? v2.y :  v2.x;
    const float dsc = odd ? v2.x : -v2.y;
    acc += vm * (useA ? A.x : A.z) + dsc * (useA ? A.y : A.w);
  }

  // ---- coalesced output: float4 over 4 consecutive n per channel -----------
  otile[wid][lane] = acc;
  __syncthreads();
  if (wid == 0) {
    float4 o4;
    o4.x = otile[0][lane]; o4.y = otile[1][lane];
    o4.z = otile[2][lane]; o4.w = otile[3][lane];
    const int c = (lane << 2) | h;       // channel = d*4 + h
    const int n0 = (rb * 4) & (NP - 1);
    *(float4*)&O[((size_t)b * DM + c) * NP + n0] = o4;
  }
}

// ---------------------------------------------------------------------------
// Kernel D: final pointwise conv (R7-proven): out = Wm @ O + bm
// ---------------------------------------------------------------------------
__global__ __launch_bounds__(256) void final_proj_kernel(
    const float* __restrict__ O, const float* __restrict__ Wm,
    const float* __restrict__ bm, float* __restrict__ out)
{
  const int tile = blockIdx.x;
  const int b    = blockIdx.y;
  const int tc = (tile >> 2) * 64;
  const int tp = (tile & 3) * 64;
  const float* X = O + (size_t)b * DM * NP;
  float* Y       = out + (size_t)b * DM * NP;

  __shared__ float Ws[2][32][64];
  __shared__ float Xs[2][32][64];
  const int tid = threadIdx.x;
  const int ty = tid >> 4, tx = tid & 15;
  const int c0 = tid >> 3;
  const int k4 = tid & 7;
  const int pX = tid & 15;
  const int kX = tid >> 4;

  float4 wA, wB, xA, xB;
  #define LOADF(K0)                                                            \
    wA = *(const float4*)&Wm[(size_t)(tc + c0)      * DM + (K0) + k4 * 4];     \
    wB = *(const float4*)&Wm[(size_t)(tc + c0 + 32) * DM + (K0) + k4 * 4];     \
    xA = *(const float4*)&X[(size_t)((K0) + kX)      * NP + tp + pX * 4];      \
    xB = *(const float4*)&X[(size_t)((K0) + kX + 16) * NP + tp + pX * 4];

  #define STOREF(BUF)                                                          \
    Ws[BUF][k4*4+0][c0] = wA.x; Ws[BUF][k4*4+1][c0] = wA.y;                    \
    Ws[BUF][k4*4+2][c0] = wA.z; Ws[BUF][k4*4+3][c0] = wA.w;                    \
    Ws[BUF][k4*4+0][c0+32] = wB.x; Ws[BUF][k4*4+1][c0+32] = wB.y;              \
    Ws[BUF][k4*4+2][c0+32] = wB.z; Ws[BUF][k4*4+3][c0+32] = wB.w;              \
    *(float4*)&Xs[BUF][kX][pX*4]      = xA;                                    \
    *(float4*)&Xs[BUF][kX+16][pX*4]   = xB;

  LOADF(0);
  STOREF(0);
  __syncthreads();

  float acc[4][4];
  #pragma unroll
  for (int i = 0; i < 4; ++i)
    #pragma unroll
    for (int j = 0; j < 4; ++j) acc[i][j] = 0.f;

  for (int ch = 0; ch < 8; ++ch) {
    const int cur = ch & 1;
    if (ch < 7) { LOADF((ch + 1) * 32); }
    #pragma unroll
    for (int kk = 0; kk < 32; ++kk) {
      float4 a = *(const float4*)&Ws[cur][kk][ty * 4];
      float4 xv = *(const float4*)&Xs[cur][kk][tx * 4];
      float av[4] = {a.x, a.y, a.z, a.w};
      float xvv[4] = {xv.x, xv.y, xv.z, xv.w};
      #pragma unroll
      for (int i = 0; i < 4; ++i)
        #pragma unroll
        for (int j = 0; j < 4; ++j) acc[i][j] += av[i] * xvv[j];
    }
    if (ch < 7) {
      STOREF(cur ^ 1);
      __syncthreads();
    }
  }

  #pragma unroll
  for (int i = 0; i < 4; ++i) {
    const int c = tc + ty * 4 + i;
    const float bb = bm[c];
    float4 o4;
    o4.x = acc[i][0] + bb; o4.y = acc[i][1] + bb;
    o4.z = acc[i][2] + bb; o4.w = acc[i][3] + bb;
    *(float4*)&Y[(size_t)c * NP + tp + tx * 4] = o4;
  }
  #undef LOADF
  #undef STOREF
}

// ---------------------------------------------------------------------------
extern "C" void kernel_launch(void* const* d_in, const int* in_sizes, int n_in,
                              void* d_out, int out_size, void* d_ws, size_t ws_size,
                              hipStream_t stream)
{
  const float* x       = (const float*)d_in[0];
  const float* source  = (const float*)d_in[1];
  const float* x_pos   = (const float*)d_in[2];
  const float* src_pos = (const float*)d_in[3];
  const float* lrf     = (const float*)d_in[4];
  const float* Wq = (const float*)d_in[5];
  const float* bq = (const float*)d_in[6];
  const float* Wk = (const float*)d_in[7];
  const float* bk = (const float*)d_in[8];
  const float* Wv = (const float*)d_in[9];
  const float* bv = (const float*)d_in[10];
  const float* Wm = (const float*)d_in[11];
  const float* bm = (const float*)d_in[12];
  const int* kptr = (const int*)d_in[13];
  float* out = (float*)d_out;

  // workspace layout (floats)
  float* ws = (float*)d_ws;
  float* Qt = ws;                         // [16][256][64]  = 262144
  float* Kt = Qt + 262144;
  float* Vt = Kt + 262144;
  float* O  = Vt + 262144;                // [4][256][256]  = 262144
  float* scores = O + 262144;             // [16][256][256] = 1048576
  // total: 8 MB

  qkv_proj_kernel<<<dim3(16, 3, 4), 256, 0, stream>>>(
      x, source, Wq, bq, Wk, bk, Wv, bv, Qt, Kt, Vt);
  score_gemm_kernel<<<dim3(16, 16), 256, 0, stream>>>(
      Qt, Kt, scores);
  attn_topk_kernel<<<dim3(1024), 256, 0, stream>>>(
      scores, Vt, x_pos, src_pos, lrf, kptr, O);
  final_proj_kernel<<<dim3(16, 4), 256, 0, stream>>>(
      O, Wm, bm, out);
}